// Round 1
// baseline (1508.643 us; speedup 1.0000x reference)
//
#include <hip/hip_runtime.h>
#include <cstdint>
#include <cstddef>

#define H_DIM 768
#define NHEADS 12
#define HSZ 64
#define PATCH 512

// ------------------------------------------------------------------
// Kernel 1: fused QKV projection.
// C = X @ W + b for W in {Wq,Wk,Wv}. X:[16384,768], W:[768,768].
// 64x64 output tile per block, BK=16, 256 threads, 4x4 per thread per matrix.
// Output written head-split: Q[bm][h][p][d], bm=0..31, h=0..11, p=0..511, d=0..63.
// ------------------------------------------------------------------
__global__ __launch_bounds__(256) void qkv_proj(
    const float* __restrict__ X,
    const float* __restrict__ Wq, const float* __restrict__ bq,
    const float* __restrict__ Wk, const float* __restrict__ bk,
    const float* __restrict__ Wv, const float* __restrict__ bv,
    float* __restrict__ Qo, float* __restrict__ Ko, float* __restrict__ Vo)
{
    __shared__ float Xs[16][72];        // transposed X tile: Xs[k][row]
    __shared__ float Ws[3][16][64];     // W tiles, row-major [k][n]

    const int tid = threadIdx.x;
    const int tx = tid & 15, ty = tid >> 4;
    const int row0 = blockIdx.y * 64;
    const int n0   = blockIdx.x * 64;   // h == blockIdx.x since HSZ==64
    const int lr = tid >> 2, lc = tid & 3;   // X tile: 64 rows x 4 float4
    const int wr = tid >> 4, wc = tid & 15;  // W tile: 16 rows x 16 float4

    float aq[4][4] = {}, ak[4][4] = {}, av[4][4] = {};

    for (int k0 = 0; k0 < H_DIM; k0 += 16) {
        float4 xv  = *(const float4*)&X [(size_t)(row0 + lr) * H_DIM + k0 + lc * 4];
        float4 wq4 = *(const float4*)&Wq[(size_t)(k0 + wr) * H_DIM + n0 + wc * 4];
        float4 wk4 = *(const float4*)&Wk[(size_t)(k0 + wr) * H_DIM + n0 + wc * 4];
        float4 wv4 = *(const float4*)&Wv[(size_t)(k0 + wr) * H_DIM + n0 + wc * 4];
        __syncthreads();  // previous iteration's readers done
        Xs[lc*4+0][lr] = xv.x; Xs[lc*4+1][lr] = xv.y;
        Xs[lc*4+2][lr] = xv.z; Xs[lc*4+3][lr] = xv.w;
        *(float4*)&Ws[0][wr][wc*4] = wq4;
        *(float4*)&Ws[1][wr][wc*4] = wk4;
        *(float4*)&Ws[2][wr][wc*4] = wv4;
        __syncthreads();
        #pragma unroll
        for (int kk = 0; kk < 16; ++kk) {
            float4 x4 = *(const float4*)&Xs[kk][ty*4];
            float4 q4 = *(const float4*)&Ws[0][kk][tx*4];
            float4 k4 = *(const float4*)&Ws[1][kk][tx*4];
            float4 v4 = *(const float4*)&Ws[2][kk][tx*4];
            const float xa[4] = {x4.x, x4.y, x4.z, x4.w};
            const float qa[4] = {q4.x, q4.y, q4.z, q4.w};
            const float ka[4] = {k4.x, k4.y, k4.z, k4.w};
            const float va[4] = {v4.x, v4.y, v4.z, v4.w};
            #pragma unroll
            for (int i = 0; i < 4; ++i)
                #pragma unroll
                for (int j = 0; j < 4; ++j) {
                    aq[i][j] += xa[i] * qa[j];
                    ak[i][j] += xa[i] * ka[j];
                    av[i][j] += xa[i] * va[j];
                }
        }
    }

    float4 bq4 = *(const float4*)&bq[n0 + tx*4];
    float4 bk4 = *(const float4*)&bk[n0 + tx*4];
    float4 bv4 = *(const float4*)&bv[n0 + tx*4];
    const float bqa[4] = {bq4.x, bq4.y, bq4.z, bq4.w};
    const float bka[4] = {bk4.x, bk4.y, bk4.z, bk4.w};
    const float bva[4] = {bv4.x, bv4.y, bv4.z, bv4.w};
    const int h = blockIdx.x;

    #pragma unroll
    for (int i = 0; i < 4; ++i) {
        int r  = row0 + ty*4 + i;
        int bm = r >> 9;          // /512
        int p  = r & 511;
        size_t base = (((size_t)bm * NHEADS + h) * PATCH + p) * HSZ + tx*4;
        float4 oq = {aq[i][0]+bqa[0], aq[i][1]+bqa[1], aq[i][2]+bqa[2], aq[i][3]+bqa[3]};
        float4 ok = {ak[i][0]+bka[0], ak[i][1]+bka[1], ak[i][2]+bka[2], ak[i][3]+bka[3]};
        float4 ov = {av[i][0]+bva[0], av[i][1]+bva[1], av[i][2]+bva[2], av[i][3]+bva[3]};
        *(float4*)&Qo[base] = oq;
        *(float4*)&Ko[base] = ok;
        *(float4*)&Vo[base] = ov;
    }
}

// ------------------------------------------------------------------
// Kernel 2: flash-style attention per (head, 64-query tile).
// Block = 256 threads. Online softmax; row-owner threads (tid<64) keep m,l.
// Writes ctx merged-head: C[(bm*512+p)*768 + h*64 + d].
// ------------------------------------------------------------------
__global__ __launch_bounds__(256) void attn(
    const float* __restrict__ Q, const float* __restrict__ K,
    const float* __restrict__ V, float* __restrict__ C)
{
    __shared__ float Qs[64][72];    // transposed: Qs[d][qrow], pre-scaled
    __shared__ float Ks[64][72];    // transposed: Ks[d][krow]
    __shared__ float Vs[64][72];    // row-major:  Vs[krow][d]
    __shared__ float Ps[64][72];    // transposed: Ps[kcol][qrow]
    __shared__ float red[64][17];
    __shared__ float mnewS[64], alphaS[64], invlS[64];

    const int tid = threadIdx.x;
    const int tx = tid & 15, ty = tid >> 4;
    const int bmh = blockIdx.x;      // 0..383 = bm*12 + h
    const int qt  = blockIdx.y;      // 0..7
    const float scale = 0.125f;      // 1/sqrt(64)
    const size_t headbase = (size_t)bmh * PATCH * HSZ;

    // load Q tile (64x64) transposed + scaled
    {
        const int c4 = tid & 15;
        #pragma unroll
        for (int rr = 0; rr < 4; ++rr) {
            int r = (tid >> 4) + rr * 16;
            int d0 = c4 * 4;
            float4 qv = *(const float4*)&Q[headbase + (size_t)(qt*64 + r)*HSZ + d0];
            Qs[d0+0][r] = qv.x * scale; Qs[d0+1][r] = qv.y * scale;
            Qs[d0+2][r] = qv.z * scale; Qs[d0+3][r] = qv.w * scale;
        }
    }

    float m_i = -INFINITY, l_i = 0.0f;     // valid in row-owner threads tid<64
    float o[4][4] = {};

    for (int kt = 0; kt < 8; ++kt) {
        // stage K (transposed) and V (row-major) tiles
        float4 kv[4], vv[4];
        const int c4 = tid & 15;
        #pragma unroll
        for (int rr = 0; rr < 4; ++rr) {
            int r = (tid >> 4) + rr * 16;
            kv[rr] = *(const float4*)&K[headbase + (size_t)(kt*64 + r)*HSZ + c4*4];
            vv[rr] = *(const float4*)&V[headbase + (size_t)(kt*64 + r)*HSZ + c4*4];
        }
        __syncthreads();  // prev iteration's Ks/Vs/Ps readers done
        #pragma unroll
        for (int rr = 0; rr < 4; ++rr) {
            int r = (tid >> 4) + rr * 16;
            int d0 = c4 * 4;
            Ks[d0+0][r] = kv[rr].x; Ks[d0+1][r] = kv[rr].y;
            Ks[d0+2][r] = kv[rr].z; Ks[d0+3][r] = kv[rr].w;
            *(float4*)&Vs[r][d0] = vv[rr];
        }
        __syncthreads();

        // S = Q K^T  (4x4 per thread; rows ty*4+i, key cols tx*4+j)
        float s[4][4] = {};
        #pragma unroll 16
        for (int d = 0; d < 64; ++d) {
            float4 q4 = *(const float4*)&Qs[d][ty*4];
            float4 k4 = *(const float4*)&Ks[d][tx*4];
            const float qa[4] = {q4.x, q4.y, q4.z, q4.w};
            const float ka[4] = {k4.x, k4.y, k4.z, k4.w};
            #pragma unroll
            for (int i = 0; i < 4; ++i)
                #pragma unroll
                for (int j = 0; j < 4; ++j)
                    s[i][j] += qa[i] * ka[j];
        }

        // partial row max
        #pragma unroll
        for (int i = 0; i < 4; ++i) {
            float pm = s[i][0];
            pm = fmaxf(pm, s[i][1]); pm = fmaxf(pm, s[i][2]); pm = fmaxf(pm, s[i][3]);
            red[ty*4+i][tx] = pm;
        }
        __syncthreads();

        if (tid < 64) {   // row owner: finish max, compute alpha
            float rowmax = red[tid][0];
            #pragma unroll
            for (int c = 1; c < 16; ++c) rowmax = fmaxf(rowmax, red[tid][c]);
            float m_new = fmaxf(m_i, rowmax);
            float alpha = __expf(m_i - m_new);
            m_i = m_new;
            l_i *= alpha;
            mnewS[tid] = m_new;
            alphaS[tid] = alpha;
        }
        __syncthreads();

        // P = exp(S - m_new); store transposed; partial row sums; rescale O
        #pragma unroll
        for (int i = 0; i < 4; ++i) {
            const int row = ty*4 + i;
            const float mn = mnewS[row];
            const float al = alphaS[row];
            float rs = 0.0f;
            #pragma unroll
            for (int j = 0; j < 4; ++j) {
                float p = __expf(s[i][j] - mn);
                Ps[tx*4+j][row] = p;
                rs += p;
            }
            red[row][tx] = rs;
            #pragma unroll
            for (int j = 0; j < 4; ++j) o[i][j] *= al;
        }
        __syncthreads();

        if (tid < 64) {   // row owner: accumulate l
            float rowsum = 0.0f;
            #pragma unroll
            for (int c = 0; c < 16; ++c) rowsum += red[tid][c];
            l_i += rowsum;
        }

        // O += P @ V   (rows ty*4+i, d-cols tx*4+j)
        #pragma unroll 16
        for (int jj = 0; jj < 64; ++jj) {
            float4 p4 = *(const float4*)&Ps[jj][ty*4];
            float4 v4 = *(const float4*)&Vs[jj][tx*4];
            const float pa[4] = {p4.x, p4.y, p4.z, p4.w};
            const float va[4] = {v4.x, v4.y, v4.z, v4.w};
            #pragma unroll
            for (int i = 0; i < 4; ++i)
                #pragma unroll
                for (int j = 0; j < 4; ++j)
                    o[i][j] += pa[i] * va[j];
        }
    }

    if (tid < 64) invlS[tid] = 1.0f / l_i;
    __syncthreads();

    const int bm = bmh / NHEADS;
    const int h  = bmh % NHEADS;
    #pragma unroll
    for (int i = 0; i < 4; ++i) {
        const int row = ty*4 + i;
        const float inv = invlS[row];
        const int p = qt*64 + row;
        size_t base = ((size_t)bm * PATCH + p) * H_DIM + h * HSZ + tx*4;
        float4 oc = {o[i][0]*inv, o[i][1]*inv, o[i][2]*inv, o[i][3]*inv};
        *(float4*)&C[base] = oc;
    }
}

// ------------------------------------------------------------------
// Kernel 3: output projection. Out = C @ Wo + bo. Row-major out [16384,768].
// ------------------------------------------------------------------
__global__ __launch_bounds__(256) void out_proj(
    const float* __restrict__ Cin,
    const float* __restrict__ Wo, const float* __restrict__ bo,
    float* __restrict__ Out)
{
    __shared__ float Xs[16][72];
    __shared__ float Ws[16][64];

    const int tid = threadIdx.x;
    const int tx = tid & 15, ty = tid >> 4;
    const int row0 = blockIdx.y * 64;
    const int n0   = blockIdx.x * 64;
    const int lr = tid >> 2, lc = tid & 3;
    const int wr = tid >> 4, wc = tid & 15;

    float acc[4][4] = {};

    for (int k0 = 0; k0 < H_DIM; k0 += 16) {
        float4 xv = *(const float4*)&Cin[(size_t)(row0 + lr) * H_DIM + k0 + lc * 4];
        float4 w4 = *(const float4*)&Wo [(size_t)(k0 + wr) * H_DIM + n0 + wc * 4];
        __syncthreads();
        Xs[lc*4+0][lr] = xv.x; Xs[lc*4+1][lr] = xv.y;
        Xs[lc*4+2][lr] = xv.z; Xs[lc*4+3][lr] = xv.w;
        *(float4*)&Ws[wr][wc*4] = w4;
        __syncthreads();
        #pragma unroll
        for (int kk = 0; kk < 16; ++kk) {
            float4 x4 = *(const float4*)&Xs[kk][ty*4];
            float4 w4r = *(const float4*)&Ws[kk][tx*4];
            const float xa[4] = {x4.x, x4.y, x4.z, x4.w};
            const float wa[4] = {w4r.x, w4r.y, w4r.z, w4r.w};
            #pragma unroll
            for (int i = 0; i < 4; ++i)
                #pragma unroll
                for (int j = 0; j < 4; ++j)
                    acc[i][j] += xa[i] * wa[j];
        }
    }

    float4 b4 = *(const float4*)&bo[n0 + tx*4];
    const float ba[4] = {b4.x, b4.y, b4.z, b4.w};
    #pragma unroll
    for (int i = 0; i < 4; ++i) {
        int r = row0 + ty*4 + i;
        float4 ov = {acc[i][0]+ba[0], acc[i][1]+ba[1], acc[i][2]+ba[2], acc[i][3]+ba[3]};
        *(float4*)&Out[(size_t)r * H_DIM + n0 + tx*4] = ov;
    }
}

extern "C" void kernel_launch(void* const* d_in, const int* in_sizes, int n_in,
                              void* d_out, int out_size, void* d_ws, size_t ws_size,
                              hipStream_t stream) {
    const float* X  = (const float*)d_in[0];
    const float* Wq = (const float*)d_in[1];
    const float* bq = (const float*)d_in[2];
    const float* Wk = (const float*)d_in[3];
    const float* bk = (const float*)d_in[4];
    const float* Wv = (const float*)d_in[5];
    const float* bv = (const float*)d_in[6];
    const float* Wo = (const float*)d_in[7];
    const float* bo = (const float*)d_in[8];
    float* Out = (float*)d_out;

    const size_t SZ = (size_t)16384 * H_DIM;   // 12,582,912 floats per buffer
    float* ws = (float*)d_ws;
    float* Qw = ws;
    float* Kw = ws + SZ;
    float* Vw = ws + 2 * SZ;
    float* Cw = ws + 3 * SZ;

    // 1) QKV projections (head-split layout)
    qkv_proj<<<dim3(12, 256), 256, 0, stream>>>(X, Wq, bq, Wk, bk, Wv, bv, Qw, Kw, Vw);
    // 2) attention per (head, query-tile)
    attn<<<dim3(384, 8), 256, 0, stream>>>(Qw, Kw, Vw, Cw);
    // 3) output projection
    out_proj<<<dim3(12, 256), 256, 0, stream>>>(Cw, Wo, bo, Out);
}

// Round 2
// 889.112 us; speedup vs baseline: 1.6968x; 1.6968x over previous
//
#include <hip/hip_runtime.h>
#include <cstdint>
#include <cstddef>

#define H_DIM 768
#define NHEADS 12
#define HSZ 64
#define PATCH 512
#define MTOT 16384                 // 8*4*512 tokens
#define SZT ((long)MTOT * H_DIM)   // elements per [16384,768] matrix

using short8 = __attribute__((ext_vector_type(8))) short;   // 8 bf16 (4 VGPRs)
using f32x4  = __attribute__((ext_vector_type(4))) float;   // MFMA accumulator
using us4    = __attribute__((ext_vector_type(4))) unsigned short;

// async global->LDS, 16B per lane; LDS dest = wave-uniform base + lane*16
#define GLL16(gp, lp) __builtin_amdgcn_global_load_lds( \
    (const __attribute__((address_space(1))) void*)(gp), \
    (__attribute__((address_space(3))) void*)(lp), 16, 0, 0)

// fp32 -> bf16 hi (truncate) + bf16 lo (RNE of remainder); hi+lo ~ 2^-17 rel err
__device__ __forceinline__ void split_f32(float x, unsigned short& h, unsigned short& l) {
    unsigned u = __float_as_uint(x);
    h = (unsigned short)(u >> 16);
    float rem = __uint_as_float(u & 0xffff0000u);
    float r = x - rem;                       // exact
    unsigned v = __float_as_uint(r);
    v += 0x7fff + ((v >> 16) & 1);           // RNE to bf16
    l = (unsigned short)(v >> 16);
}

// ------------------------------------------------------------------
// prep_x: X fp32 [16384][768] -> Xhi, Xlo bf16 row-major (stored in d_out)
// ------------------------------------------------------------------
__global__ __launch_bounds__(256) void prep_x(const float* __restrict__ X,
                                              unsigned short* __restrict__ Xhi,
                                              unsigned short* __restrict__ Xlo)
{
    const long i = ((long)blockIdx.x * 256 + threadIdx.x) * 8;
    float4 a = *(const float4*)&X[i];
    float4 b = *(const float4*)&X[i + 4];
    float xs[8] = {a.x, a.y, a.z, a.w, b.x, b.y, b.z, b.w};
    unsigned short h[8], l[8];
    #pragma unroll
    for (int j = 0; j < 8; ++j) split_f32(xs[j], h[j], l[j]);
    us4 h0, h1, l0, l1;
    #pragma unroll
    for (int j = 0; j < 4; ++j) { h0[j] = h[j]; h1[j] = h[j+4]; l0[j] = l[j]; l1[j] = l[j+4]; }
    *(us4*)&Xhi[i] = h0; *(us4*)&Xhi[i + 4] = h1;
    *(us4*)&Xlo[i] = l0; *(us4*)&Xlo[i + 4] = l1;
}

// ------------------------------------------------------------------
// prep_w: W fp32 [k][n] -> transposed split Whi/Wlo bf16 [n][k]
// 64x64 tile per block via padded LDS transpose.
// ------------------------------------------------------------------
__global__ __launch_bounds__(256) void prep_w(const float* __restrict__ W,
                                              unsigned short* __restrict__ Whi,
                                              unsigned short* __restrict__ Wlo)
{
    __shared__ float T[64][65];
    const int kt = blockIdx.x * 64, nt = blockIdx.y * 64;
    const int tid = threadIdx.x;
    const int r = tid >> 2, c16 = (tid & 3) * 16;
    #pragma unroll
    for (int j = 0; j < 4; ++j) {
        float4 v = *(const float4*)&W[(long)(kt + r) * H_DIM + nt + c16 + j * 4];
        T[r][c16 + j*4 + 0] = v.x; T[r][c16 + j*4 + 1] = v.y;
        T[r][c16 + j*4 + 2] = v.z; T[r][c16 + j*4 + 3] = v.w;
    }
    __syncthreads();
    unsigned short* ph = &Whi[(long)(nt + r) * H_DIM + kt + c16];
    unsigned short* pl = &Wlo[(long)(nt + r) * H_DIM + kt + c16];
    #pragma unroll
    for (int j = 0; j < 16; ++j) {
        unsigned short hh, ll;
        split_f32(T[c16 + j][r], hh, ll);
        ph[j] = hh; pl[j] = ll;
    }
}

// ------------------------------------------------------------------
// gemm3: C = (Ahi+Alo) @ (Bhi+Blo)^T + bias via 3 bf16 MFMA passes.
// 128x128 tile / block, 4 waves (2x2), 64x64 per wave, BK=32.
// MODE 0: A row-major [MTOT][768]; epilogue head-split fp32 [bm][h][p][d].
// MODE 1: A in ctx-tile layout (from attn); epilogue row-major fp32.
// ------------------------------------------------------------------
template<int MODE>
__global__ __launch_bounds__(256, 2) void gemm3(
    const unsigned short* __restrict__ Ahi, const unsigned short* __restrict__ Alo,
    const unsigned short* __restrict__ Bhi, const unsigned short* __restrict__ Blo,
    const float* __restrict__ bias, float* __restrict__ out)
{
    __shared__ unsigned short As[2][4096];   // [hi/lo][m*32 + k], 8 KB each
    __shared__ unsigned short Bs[2][4096];   // [hi/lo][n*32 + k]

    const int tid  = threadIdx.x;
    const int lane = tid & 63;
    const int wv   = tid >> 6;
    const int wr   = wv >> 1, wc = wv & 1;
    const int q    = lane >> 4, l15 = lane & 15;
    const int m0   = blockIdx.y * 128;
    const int n0   = blockIdx.x * 128;

    const int sRow = tid >> 2;   // staging: 64 rows x 4 x 16B per issue
    const int sKg  = tid & 3;

    char* ldsA = (char*)(&As[0][0]) + (wv << 10);
    char* ldsB = (char*)(&Bs[0][0]) + (wv << 10);

    const int bOff0 = (n0 + sRow) * H_DIM + sKg * 8;
    const int bOff1 = (n0 + 64 + sRow) * H_DIM + sKg * 8;
    const int aOff0 = (m0 + sRow) * H_DIM + sKg * 8;        // MODE 0 only
    const int aOff1 = (m0 + 64 + sRow) * H_DIM + sKg * 8;

    f32x4 acc[4][4];
    #pragma unroll
    for (int i = 0; i < 4; ++i)
        #pragma unroll
        for (int j = 0; j < 4; ++j) acc[i][j] = 0;

    for (int k0 = 0; k0 < H_DIM; k0 += 32) {
        if (MODE == 0) {
            GLL16(Ahi + aOff0 + k0, ldsA);
            GLL16(Ahi + aOff1 + k0, ldsA + 4096);
            GLL16(Alo + aOff0 + k0, ldsA + 8192);
            GLL16(Alo + aOff1 + k0, ldsA + 12288);
        } else {
            // ctx tiles: [bmh][qt] blocks of (hi[64][64], lo[64][64]) bf16
            const int h = k0 >> 6;
            const int d = (k0 & 63) + sKg * 8;
            const int tok0 = m0 + sRow, tok1 = m0 + 64 + sRow;
            const int t0 = (((tok0 >> 9) * NHEADS + h) * 8 + ((tok0 >> 6) & 7)) * 8192
                         + (tok0 & 63) * 64 + d;
            const int t1 = (((tok1 >> 9) * NHEADS + h) * 8 + ((tok1 >> 6) & 7)) * 8192
                         + (tok1 & 63) * 64 + d;
            GLL16(Ahi + t0, ldsA);
            GLL16(Ahi + t1, ldsA + 4096);
            GLL16(Alo + t0, ldsA + 8192);
            GLL16(Alo + t1, ldsA + 12288);
        }
        GLL16(Bhi + bOff0 + k0, ldsB);
        GLL16(Bhi + bOff1 + k0, ldsB + 4096);
        GLL16(Blo + bOff0 + k0, ldsB + 8192);
        GLL16(Blo + bOff1 + k0, ldsB + 12288);
        __syncthreads();   // drains vmcnt(0): global_load_lds complete + visible

        short8 ah[4], al[4], bh[4], bl[4];
        #pragma unroll
        for (int t = 0; t < 4; ++t) {
            const int mr = wr * 64 + t * 16 + l15;
            ah[t] = *(const short8*)&As[0][mr * 32 + q * 8];
            al[t] = *(const short8*)&As[1][mr * 32 + q * 8];
            const int nr = wc * 64 + t * 16 + l15;
            bh[t] = *(const short8*)&Bs[0][nr * 32 + q * 8];
            bl[t] = *(const short8*)&Bs[1][nr * 32 + q * 8];
        }
        #pragma unroll
        for (int mt = 0; mt < 4; ++mt)
            #pragma unroll
            for (int nt = 0; nt < 4; ++nt) {
                acc[mt][nt] = __builtin_amdgcn_mfma_f32_16x16x32_bf16(ah[mt], bh[nt], acc[mt][nt], 0, 0, 0);
                acc[mt][nt] = __builtin_amdgcn_mfma_f32_16x16x32_bf16(ah[mt], bl[nt], acc[mt][nt], 0, 0, 0);
                acc[mt][nt] = __builtin_amdgcn_mfma_f32_16x16x32_bf16(al[mt], bh[nt], acc[mt][nt], 0, 0, 0);
            }
        __syncthreads();   // all reads done before next stage overwrites
    }

    // epilogue: C/D layout col = lane&15, row = quad*4 + reg (verified m89/m91)
    #pragma unroll
    for (int nt = 0; nt < 4; ++nt) {
        const int col = n0 + wc * 64 + nt * 16 + l15;
        const float bcol = bias[col];
        if (MODE == 0) {
            const int h = col >> 6, d = col & 63;
            #pragma unroll
            for (int mt = 0; mt < 4; ++mt) {
                const int rowB = m0 + wr * 64 + mt * 16 + q * 4;
                #pragma unroll
                for (int r = 0; r < 4; ++r) {
                    const int row = rowB + r;
                    const int bm = row >> 9, p = row & 511;
                    out[(((long)bm * NHEADS + h) * PATCH + p) * HSZ + d] = acc[mt][nt][r] + bcol;
                }
            }
        } else {
            #pragma unroll
            for (int mt = 0; mt < 4; ++mt) {
                const int rowB = m0 + wr * 64 + mt * 16 + q * 4;
                #pragma unroll
                for (int r = 0; r < 4; ++r)
                    out[(long)(rowB + r) * H_DIM + col] = acc[mt][nt][r] + bcol;
            }
        }
    }
}

// ------------------------------------------------------------------
// attn: flash-style fp32 attention per (head, 64-query tile).
// Epilogue writes ctx as bf16 hi/lo tiles IN PLACE over the Q buffer
// (each block only overwrites the Q tile it alone consumed).
// ------------------------------------------------------------------
__global__ __launch_bounds__(256) void attn(
    const float* __restrict__ Q, const float* __restrict__ K,
    const float* __restrict__ V, unsigned short* __restrict__ Cb)
{
    __shared__ float Qs[64][72];
    __shared__ float Ks[64][72];
    __shared__ float Vs[64][72];
    __shared__ float Ps[64][72];
    __shared__ float red[64][17];
    __shared__ float mnewS[64], alphaS[64], invlS[64];

    const int tid = threadIdx.x;
    const int tx = tid & 15, ty = tid >> 4;
    const int bmh = blockIdx.x;
    const int qt  = blockIdx.y;
    const float scale = 0.125f;
    const size_t headbase = (size_t)bmh * PATCH * HSZ;

    {
        const int c4 = tid & 15;
        #pragma unroll
        for (int rr = 0; rr < 4; ++rr) {
            int r = (tid >> 4) + rr * 16;
            int d0 = c4 * 4;
            float4 qv = *(const float4*)&Q[headbase + (size_t)(qt*64 + r)*HSZ + d0];
            Qs[d0+0][r] = qv.x * scale; Qs[d0+1][r] = qv.y * scale;
            Qs[d0+2][r] = qv.z * scale; Qs[d0+3][r] = qv.w * scale;
        }
    }

    float m_i = -INFINITY, l_i = 0.0f;
    float o[4][4] = {};

    for (int kt = 0; kt < 8; ++kt) {
        float4 kv[4], vv[4];
        const int c4 = tid & 15;
        #pragma unroll
        for (int rr = 0; rr < 4; ++rr) {
            int r = (tid >> 4) + rr * 16;
            kv[rr] = *(const float4*)&K[headbase + (size_t)(kt*64 + r)*HSZ + c4*4];
            vv[rr] = *(const float4*)&V[headbase + (size_t)(kt*64 + r)*HSZ + c4*4];
        }
        __syncthreads();
        #pragma unroll
        for (int rr = 0; rr < 4; ++rr) {
            int r = (tid >> 4) + rr * 16;
            int d0 = c4 * 4;
            Ks[d0+0][r] = kv[rr].x; Ks[d0+1][r] = kv[rr].y;
            Ks[d0+2][r] = kv[rr].z; Ks[d0+3][r] = kv[rr].w;
            *(float4*)&Vs[r][d0] = vv[rr];
        }
        __syncthreads();

        float s[4][4] = {};
        #pragma unroll 16
        for (int d = 0; d < 64; ++d) {
            float4 q4 = *(const float4*)&Qs[d][ty*4];
            float4 k4 = *(const float4*)&Ks[d][tx*4];
            const float qa[4] = {q4.x, q4.y, q4.z, q4.w};
            const float ka[4] = {k4.x, k4.y, k4.z, k4.w};
            #pragma unroll
            for (int i = 0; i < 4; ++i)
                #pragma unroll
                for (int j = 0; j < 4; ++j)
                    s[i][j] += qa[i] * ka[j];
        }

        #pragma unroll
        for (int i = 0; i < 4; ++i) {
            float pm = s[i][0];
            pm = fmaxf(pm, s[i][1]); pm = fmaxf(pm, s[i][2]); pm = fmaxf(pm, s[i][3]);
            red[ty*4+i][tx] = pm;
        }
        __syncthreads();

        if (tid < 64) {
            float rowmax = red[tid][0];
            #pragma unroll
            for (int c = 1; c < 16; ++c) rowmax = fmaxf(rowmax, red[tid][c]);
            float m_new = fmaxf(m_i, rowmax);
            float alpha = __expf(m_i - m_new);
            m_i = m_new;
            l_i *= alpha;
            mnewS[tid] = m_new;
            alphaS[tid] = alpha;
        }
        __syncthreads();

        #pragma unroll
        for (int i = 0; i < 4; ++i) {
            const int row = ty*4 + i;
            const float mn = mnewS[row];
            const float al = alphaS[row];
            float rs = 0.0f;
            #pragma unroll
            for (int j = 0; j < 4; ++j) {
                float p = __expf(s[i][j] - mn);
                Ps[tx*4+j][row] = p;
                rs += p;
            }
            red[row][tx] = rs;
            #pragma unroll
            for (int j = 0; j < 4; ++j) o[i][j] *= al;
        }
        __syncthreads();

        if (tid < 64) {
            float rowsum = 0.0f;
            #pragma unroll
            for (int c = 0; c < 16; ++c) rowsum += red[tid][c];
            l_i += rowsum;
        }

        #pragma unroll 16
        for (int jj = 0; jj < 64; ++jj) {
            float4 p4 = *(const float4*)&Ps[jj][ty*4];
            float4 v4 = *(const float4*)&Vs[jj][tx*4];
            const float pa[4] = {p4.x, p4.y, p4.z, p4.w};
            const float va[4] = {v4.x, v4.y, v4.z, v4.w};
            #pragma unroll
            for (int i = 0; i < 4; ++i)
                #pragma unroll
                for (int j = 0; j < 4; ++j)
                    o[i][j] += pa[i] * va[j];
        }
    }

    if (tid < 64) invlS[tid] = 1.0f / l_i;
    __syncthreads();

    // write ctx tile as bf16 hi/lo planes over this block's own Q region
    unsigned short* tp = Cb + (long)(bmh * 8 + qt) * 8192;
    #pragma unroll
    for (int i = 0; i < 4; ++i) {
        const int row = ty*4 + i;
        const float inv = invlS[row];
        us4 hv, lv;
        #pragma unroll
        for (int j = 0; j < 4; ++j) {
            unsigned short hh, ll;
            split_f32(o[i][j] * inv, hh, ll);
            hv[j] = hh; lv[j] = ll;
        }
        *(us4*)&tp[row * 64 + tx * 4] = hv;
        *(us4*)&tp[4096 + row * 64 + tx * 4] = lv;
    }
}

extern "C" void kernel_launch(void* const* d_in, const int* in_sizes, int n_in,
                              void* d_out, int out_size, void* d_ws, size_t ws_size,
                              hipStream_t stream) {
    const float* X  = (const float*)d_in[0];
    const float* Wq = (const float*)d_in[1]; const float* bq = (const float*)d_in[2];
    const float* Wk = (const float*)d_in[3]; const float* bk = (const float*)d_in[4];
    const float* Wv = (const float*)d_in[5]; const float* bv = (const float*)d_in[6];
    const float* Wo = (const float*)d_in[7]; const float* bo = (const float*)d_in[8];

    float* ws = (float*)d_ws;
    float* Qw = ws;                 // fp32 [bm][h][p][d]; later overwritten by ctx hi/lo tiles
    float* Kw = ws + SZT;
    float* Vw = ws + 2 * SZT;
    unsigned short* Wt = (unsigned short*)(ws + 3 * SZT);
    const long WP = (long)H_DIM * H_DIM;
    unsigned short* WqH = Wt;          unsigned short* WqL = Wt + WP;
    unsigned short* WkH = Wt + 2 * WP; unsigned short* WkL = Wt + 3 * WP;
    unsigned short* WvH = Wt + 4 * WP; unsigned short* WvL = Wt + 5 * WP;
    unsigned short* WoH = Wt + 6 * WP; unsigned short* WoL = Wt + 7 * WP;

    // X splits live in d_out (dead until the final projection overwrites it)
    unsigned short* Xhi = (unsigned short*)d_out;
    unsigned short* Xlo = Xhi + SZT;

    prep_x<<<(int)(SZT / 2048), 256, 0, stream>>>(X, Xhi, Xlo);
    dim3 wgrid(12, 12);
    prep_w<<<wgrid, 256, 0, stream>>>(Wq, WqH, WqL);
    prep_w<<<wgrid, 256, 0, stream>>>(Wk, WkH, WkL);
    prep_w<<<wgrid, 256, 0, stream>>>(Wv, WvH, WvL);
    prep_w<<<wgrid, 256, 0, stream>>>(Wo, WoH, WoL);

    dim3 ggrid(6, 128);
    gemm3<0><<<ggrid, 256, 0, stream>>>(Xhi, Xlo, WqH, WqL, bq, Qw);
    gemm3<0><<<ggrid, 256, 0, stream>>>(Xhi, Xlo, WkH, WkL, bk, Kw);
    gemm3<0><<<ggrid, 256, 0, stream>>>(Xhi, Xlo, WvH, WvL, bv, Vw);

    attn<<<dim3(384, 8), 256, 0, stream>>>(Qw, Kw, Vw, (unsigned short*)Qw);

    gemm3<1><<<ggrid, 256, 0, stream>>>((unsigned short*)Qw, (unsigned short*)Qw + 4096,
                                        WoH, WoL, bo, (float*)d_out);
}

// Round 3
// 587.492 us; speedup vs baseline: 2.5679x; 1.5134x over previous
//
#include <hip/hip_runtime.h>
#include <cstdint>
#include <cstddef>

#define H_DIM 768
#define NHEADS 12
#define HSZ 64
#define PATCH 512
#define MTOT 16384                 // 8*4*512 tokens
#define SZT ((long)MTOT * H_DIM)   // elements per [16384,768] matrix

using short8 = __attribute__((ext_vector_type(8))) short;   // 8 bf16 (4 VGPRs)
using f32x4  = __attribute__((ext_vector_type(4))) float;   // MFMA accumulator
using us4    = __attribute__((ext_vector_type(4))) unsigned short;

// async global->LDS, 16B per lane; LDS dest = wave-uniform base + lane*16
#define GLL16(gp, lp) __builtin_amdgcn_global_load_lds( \
    (const __attribute__((address_space(1))) void*)(gp), \
    (__attribute__((address_space(3))) void*)(lp), 16, 0, 0)

// fp32 -> bf16 hi (truncate) + bf16 lo (RNE of remainder); hi+lo ~ 2^-17 rel err
__device__ __forceinline__ void split_f32(float x, unsigned short& h, unsigned short& l) {
    unsigned u = __float_as_uint(x);
    h = (unsigned short)(u >> 16);
    float rem = __uint_as_float(u & 0xffff0000u);
    float r = x - rem;                       // exact
    unsigned v = __float_as_uint(r);
    v += 0x7fff + ((v >> 16) & 1);           // RNE to bf16
    l = (unsigned short)(v >> 16);
}

__device__ __forceinline__ unsigned short bf16rne(float x) {
    unsigned v = __float_as_uint(x);
    v += 0x7fff + ((v >> 16) & 1);
    return (unsigned short)(v >> 16);
}

// ------------------------------------------------------------------
// prep_x: X fp32 [16384][768] -> Xhi, Xlo bf16 row-major (stored in d_out)
// ------------------------------------------------------------------
__global__ __launch_bounds__(256) void prep_x(const float* __restrict__ X,
                                              unsigned short* __restrict__ Xhi,
                                              unsigned short* __restrict__ Xlo)
{
    const long i = ((long)blockIdx.x * 256 + threadIdx.x) * 8;
    float4 a = *(const float4*)&X[i];
    float4 b = *(const float4*)&X[i + 4];
    float xs[8] = {a.x, a.y, a.z, a.w, b.x, b.y, b.z, b.w};
    unsigned short h[8], l[8];
    #pragma unroll
    for (int j = 0; j < 8; ++j) split_f32(xs[j], h[j], l[j]);
    us4 h0, h1, l0, l1;
    #pragma unroll
    for (int j = 0; j < 4; ++j) { h0[j] = h[j]; h1[j] = h[j+4]; l0[j] = l[j]; l1[j] = l[j+4]; }
    *(us4*)&Xhi[i] = h0; *(us4*)&Xhi[i + 4] = h1;
    *(us4*)&Xlo[i] = l0; *(us4*)&Xlo[i + 4] = l1;
}

// ------------------------------------------------------------------
// prep_w: W fp32 [k][n] -> transposed split Whi/Wlo bf16 [n][k]
// ------------------------------------------------------------------
__global__ __launch_bounds__(256) void prep_w(const float* __restrict__ W,
                                              unsigned short* __restrict__ Whi,
                                              unsigned short* __restrict__ Wlo)
{
    __shared__ float T[64][65];
    const int kt = blockIdx.x * 64, nt = blockIdx.y * 64;
    const int tid = threadIdx.x;
    const int r = tid >> 2, c16 = (tid & 3) * 16;
    #pragma unroll
    for (int j = 0; j < 4; ++j) {
        float4 v = *(const float4*)&W[(long)(kt + r) * H_DIM + nt + c16 + j * 4];
        T[r][c16 + j*4 + 0] = v.x; T[r][c16 + j*4 + 1] = v.y;
        T[r][c16 + j*4 + 2] = v.z; T[r][c16 + j*4 + 3] = v.w;
    }
    __syncthreads();
    unsigned short* ph = &Whi[(long)(nt + r) * H_DIM + kt + c16];
    unsigned short* pl = &Wlo[(long)(nt + r) * H_DIM + kt + c16];
    #pragma unroll
    for (int j = 0; j < 16; ++j) {
        unsigned short hh, ll;
        split_f32(T[c16 + j][r], hh, ll);
        ph[j] = hh; pl[j] = ll;
    }
}

// ------------------------------------------------------------------
// gemm3: C = (Ahi+Alo) @ (Bhi+Blo)^T, + bias, *scale; 3 bf16 MFMA passes.
// 128x128 tile / block, 4 waves (2x2), BK=32.
// MODE 0: A row-major; out split planes [bmh][p][d]           (K)
// MODE 2: A row-major; out split planes transposed [bmh][d][p] (V)
// MODE 3: A row-major; out tile-interleaved hi/lo [bmh][qt]{hi4096,lo4096} (Q, pre-scaled)
// MODE 1: A ctx-tile layout; out fp32 row-major                (final proj)
// ------------------------------------------------------------------
template<int MODE>
__global__ __launch_bounds__(256, 2) void gemm3(
    const unsigned short* __restrict__ Ahi, const unsigned short* __restrict__ Alo,
    const unsigned short* __restrict__ Bhi, const unsigned short* __restrict__ Blo,
    const float* __restrict__ bias, float scale,
    float* __restrict__ outF,
    unsigned short* __restrict__ outH, unsigned short* __restrict__ outL)
{
    __shared__ unsigned short As[2][4096];
    __shared__ unsigned short Bs[2][4096];

    const int tid  = threadIdx.x;
    const int lane = tid & 63;
    const int wv   = tid >> 6;
    const int wr   = wv >> 1, wc = wv & 1;
    const int q    = lane >> 4, l15 = lane & 15;
    const int m0   = blockIdx.y * 128;
    const int n0   = blockIdx.x * 128;

    const int sRow = tid >> 2;
    const int sKg  = tid & 3;

    char* ldsA = (char*)(&As[0][0]) + (wv << 10);
    char* ldsB = (char*)(&Bs[0][0]) + (wv << 10);

    const int bOff0 = (n0 + sRow) * H_DIM + sKg * 8;
    const int bOff1 = (n0 + 64 + sRow) * H_DIM + sKg * 8;
    const int aOff0 = (m0 + sRow) * H_DIM + sKg * 8;
    const int aOff1 = (m0 + 64 + sRow) * H_DIM + sKg * 8;

    f32x4 acc[4][4];
    #pragma unroll
    for (int i = 0; i < 4; ++i)
        #pragma unroll
        for (int j = 0; j < 4; ++j) acc[i][j] = 0;

    for (int k0 = 0; k0 < H_DIM; k0 += 32) {
        if (MODE != 1) {
            GLL16(Ahi + aOff0 + k0, ldsA);
            GLL16(Ahi + aOff1 + k0, ldsA + 4096);
            GLL16(Alo + aOff0 + k0, ldsA + 8192);
            GLL16(Alo + aOff1 + k0, ldsA + 12288);
        } else {
            const int h = k0 >> 6;
            const int d = (k0 & 63) + sKg * 8;
            const int tok0 = m0 + sRow, tok1 = m0 + 64 + sRow;
            const int t0 = (((tok0 >> 9) * NHEADS + h) * 8 + ((tok0 >> 6) & 7)) * 8192
                         + (tok0 & 63) * 64 + d;
            const int t1 = (((tok1 >> 9) * NHEADS + h) * 8 + ((tok1 >> 6) & 7)) * 8192
                         + (tok1 & 63) * 64 + d;
            GLL16(Ahi + t0, ldsA);
            GLL16(Ahi + t1, ldsA + 4096);
            GLL16(Alo + t0, ldsA + 8192);
            GLL16(Alo + t1, ldsA + 12288);
        }
        GLL16(Bhi + bOff0 + k0, ldsB);
        GLL16(Bhi + bOff1 + k0, ldsB + 4096);
        GLL16(Blo + bOff0 + k0, ldsB + 8192);
        GLL16(Blo + bOff1 + k0, ldsB + 12288);
        __syncthreads();

        short8 ah[4], al[4], bh[4], bl[4];
        #pragma unroll
        for (int t = 0; t < 4; ++t) {
            const int mr = wr * 64 + t * 16 + l15;
            ah[t] = *(const short8*)&As[0][mr * 32 + q * 8];
            al[t] = *(const short8*)&As[1][mr * 32 + q * 8];
            const int nr = wc * 64 + t * 16 + l15;
            bh[t] = *(const short8*)&Bs[0][nr * 32 + q * 8];
            bl[t] = *(const short8*)&Bs[1][nr * 32 + q * 8];
        }
        #pragma unroll
        for (int mt = 0; mt < 4; ++mt)
            #pragma unroll
            for (int nt = 0; nt < 4; ++nt) {
                acc[mt][nt] = __builtin_amdgcn_mfma_f32_16x16x32_bf16(ah[mt], bh[nt], acc[mt][nt], 0, 0, 0);
                acc[mt][nt] = __builtin_amdgcn_mfma_f32_16x16x32_bf16(ah[mt], bl[nt], acc[mt][nt], 0, 0, 0);
                acc[mt][nt] = __builtin_amdgcn_mfma_f32_16x16x32_bf16(al[mt], bh[nt], acc[mt][nt], 0, 0, 0);
            }
        __syncthreads();
    }

    // epilogue: C/D layout col = lane&15, row = quad*4 + reg
    #pragma unroll
    for (int nt = 0; nt < 4; ++nt) {
        const int col = n0 + wc * 64 + nt * 16 + l15;
        const float bcol = bias[col];
        const int h = col >> 6, d = col & 63;
        #pragma unroll
        for (int mt = 0; mt < 4; ++mt) {
            const int rowB = m0 + wr * 64 + mt * 16 + q * 4;
            #pragma unroll
            for (int r = 0; r < 4; ++r) {
                const int row = rowB + r;
                const float val = (acc[mt][nt][r] + bcol) * scale;
                if (MODE == 1) {
                    outF[(long)row * H_DIM + col] = val;
                } else {
                    unsigned short hh, ll;
                    split_f32(val, hh, ll);
                    const int bm = row >> 9, p = row & 511;
                    if (MODE == 0) {
                        const long idx = (((long)bm * NHEADS + h) * PATCH + p) * HSZ + d;
                        outH[idx] = hh; outL[idx] = ll;
                    } else if (MODE == 2) {
                        const long idx = (((long)bm * NHEADS + h) * HSZ + d) * PATCH + p;
                        outH[idx] = hh; outL[idx] = ll;
                    } else {  // MODE 3: Q tiles
                        const long idx = (((long)bm * NHEADS + h) * 8 + (p >> 6)) * 8192
                                       + (long)(p & 63) * 64 + d;
                        outH[idx] = hh; outH[idx + 4096] = ll;
                    }
                }
            }
        }
    }
}

// ------------------------------------------------------------------
// attn_mfma: flash attention, MFMA everywhere.
// Block: 4 waves (wr,wc 2x2) over 128 q-rows x 64-key tiles, 8 key iters.
// Q pre-scaled by 0.125*log2e, stored as hi/lo tiles; softmax in base-2.
// K staged [key][d] hi/lo, V staged [d][key] hi/lo, XOR-swizzled chunks.
// ctx written as hi/lo tiles in place over the block's own Q tiles.
// ------------------------------------------------------------------
__global__ __launch_bounds__(256, 2) void attn_mfma(
    const unsigned short* __restrict__ Qt,
    const unsigned short* __restrict__ Kh, const unsigned short* __restrict__ Kl,
    const unsigned short* __restrict__ Vh, const unsigned short* __restrict__ Vl,
    unsigned short* __restrict__ Ctx)
{
    __shared__ unsigned short Ks[2][4096];   // [pl][key*64 + swz-chunk*8]
    __shared__ unsigned short Vs[2][4096];   // [pl][d*64 + swz-chunk*8]
    __shared__ unsigned short Ps[128 * 72];  // P bf16, padded stride 72
    __shared__ float red[128][2];            // cross-wave row max / sum

    const int tid  = threadIdx.x;
    const int lane = tid & 63;
    const int wv   = tid >> 6;
    const int wr   = wv >> 1, wc = wv & 1;
    const int q    = lane >> 4, l15 = lane & 15;
    const int bmh  = blockIdx.x;
    const int qt2  = blockIdx.y;

    // ---- Q fragments (loop-invariant, in registers) ----
    short8 qh[4][2], ql[4][2];
    const long qtile = ((long)bmh * 8 + qt2 * 2 + wr) * 8192;
    #pragma unroll
    for (int mt = 0; mt < 4; ++mt)
        #pragma unroll
        for (int ks = 0; ks < 2; ++ks) {
            const long o = qtile + (mt * 16 + l15) * 64 + ks * 32 + q * 8;
            qh[mt][ks] = *(const short8*)&Qt[o];
            ql[mt][ks] = *(const short8*)&Qt[o + 4096];
        }

    f32x4 ctx[4][2];
    float m_cur[4][4], l_cur[4][4];
    #pragma unroll
    for (int mt = 0; mt < 4; ++mt) {
        ctx[mt][0] = 0; ctx[mt][1] = 0;
        #pragma unroll
        for (int r = 0; r < 4; ++r) { m_cur[mt][r] = -INFINITY; l_cur[mt][r] = 0.0f; }
    }

    const long khead = (long)bmh * PATCH * HSZ;
    const long vhead = (long)bmh * HSZ * PATCH;
    const int srow   = tid >> 3;                               // 0..31
    const int gchunk = ((tid & 7) ^ (srow & 7)) * 8;           // swizzled source chunk
    char* dK0 = (char*)&Ks[0][0] + (wv << 10);
    char* dK1 = (char*)&Ks[1][0] + (wv << 10);
    char* dV0 = (char*)&Vs[0][0] + (wv << 10);
    char* dV1 = (char*)&Vs[1][0] + (wv << 10);

    for (int kt = 0; kt < 8; ++kt) {
        __syncthreads();   // prev iter's PV reads of Vs/Ps complete
        {
            const long kb = khead + (long)kt * 64 * 64;
            GLL16(Kh + kb + (long)srow * 64 + gchunk,        dK0);
            GLL16(Kh + kb + (long)(srow + 32) * 64 + gchunk, dK0 + 4096);
            GLL16(Kl + kb + (long)srow * 64 + gchunk,        dK1);
            GLL16(Kl + kb + (long)(srow + 32) * 64 + gchunk, dK1 + 4096);
            const long vb = vhead + (long)kt * 64;
            GLL16(Vh + vb + (long)srow * PATCH + gchunk,        dV0);
            GLL16(Vh + vb + (long)(srow + 32) * PATCH + gchunk, dV0 + 4096);
            GLL16(Vl + vb + (long)srow * PATCH + gchunk,        dV1);
            GLL16(Vl + vb + (long)(srow + 32) * PATCH + gchunk, dV1 + 4096);
        }
        __syncthreads();   // staging landed (barrier drains vmcnt)

        // ---- S = Q K^T (3-pass) : wave (wr,wc) -> rows wr*64+, keys wc*32+ ----
        f32x4 s[4][2];
        #pragma unroll
        for (int mt = 0; mt < 4; ++mt) { s[mt][0] = 0; s[mt][1] = 0; }
        short8 kfh[2][2], kfl[2][2];
        #pragma unroll
        for (int nt = 0; nt < 2; ++nt)
            #pragma unroll
            for (int ks = 0; ks < 2; ++ks) {
                const int key = wc * 32 + nt * 16 + l15;
                const int phys = (q + ks * 4) ^ (key & 7);
                kfh[nt][ks] = *(const short8*)&Ks[0][key * 64 + phys * 8];
                kfl[nt][ks] = *(const short8*)&Ks[1][key * 64 + phys * 8];
            }
        #pragma unroll
        for (int mt = 0; mt < 4; ++mt)
            #pragma unroll
            for (int nt = 0; nt < 2; ++nt)
                #pragma unroll
                for (int ks = 0; ks < 2; ++ks) {
                    s[mt][nt] = __builtin_amdgcn_mfma_f32_16x16x32_bf16(qh[mt][ks], kfh[nt][ks], s[mt][nt], 0, 0, 0);
                    s[mt][nt] = __builtin_amdgcn_mfma_f32_16x16x32_bf16(qh[mt][ks], kfl[nt][ks], s[mt][nt], 0, 0, 0);
                    s[mt][nt] = __builtin_amdgcn_mfma_f32_16x16x32_bf16(ql[mt][ks], kfh[nt][ks], s[mt][nt], 0, 0, 0);
                }

        // ---- row max: in-quad shuffle reduce, cross-wave via LDS ----
        #pragma unroll
        for (int mt = 0; mt < 4; ++mt)
            #pragma unroll
            for (int r = 0; r < 4; ++r) {
                float v = fmaxf(s[mt][0][r], s[mt][1][r]);
                v = fmaxf(v, __shfl_xor(v, 1));
                v = fmaxf(v, __shfl_xor(v, 2));
                v = fmaxf(v, __shfl_xor(v, 4));
                v = fmaxf(v, __shfl_xor(v, 8));
                if (l15 == 0) red[wr * 64 + mt * 16 + q * 4 + r][wc] = v;
            }
        __syncthreads();

        // ---- p = exp2(s - m_new); online rescale; write P (bf16) ----
        #pragma unroll
        for (int mt = 0; mt < 4; ++mt)
            #pragma unroll
            for (int r = 0; r < 4; ++r) {
                const int row = wr * 64 + mt * 16 + q * 4 + r;
                const float2 rd = *(const float2*)&red[row][0];
                const float mn = fmaxf(m_cur[mt][r], fmaxf(rd.x, rd.y));
                const float al = __builtin_amdgcn_exp2f(m_cur[mt][r] - mn);
                m_cur[mt][r] = mn;
                const float p0 = __builtin_amdgcn_exp2f(s[mt][0][r] - mn);
                const float p1 = __builtin_amdgcn_exp2f(s[mt][1][r] - mn);
                l_cur[mt][r] = l_cur[mt][r] * al + p0 + p1;
                ctx[mt][0][r] *= al;
                ctx[mt][1][r] *= al;
                Ps[row * 72 + wc * 32 + l15]      = bf16rne(p0);
                Ps[row * 72 + wc * 32 + 16 + l15] = bf16rne(p1);
            }
        __syncthreads();

        // ---- ctx += P V (2-pass) : wave -> rows wr*64+, d-cols wc*32+ ----
        short8 pf[4][2], vfh[2][2], vfl[2][2];
        #pragma unroll
        for (int mt = 0; mt < 4; ++mt)
            #pragma unroll
            for (int ks = 0; ks < 2; ++ks)
                pf[mt][ks] = *(const short8*)&Ps[(wr * 64 + mt * 16 + l15) * 72 + ks * 32 + q * 8];
        #pragma unroll
        for (int nt = 0; nt < 2; ++nt)
            #pragma unroll
            for (int ks = 0; ks < 2; ++ks) {
                const int d = wc * 32 + nt * 16 + l15;
                const int phys = (q + ks * 4) ^ (d & 7);
                vfh[nt][ks] = *(const short8*)&Vs[0][d * 64 + phys * 8];
                vfl[nt][ks] = *(const short8*)&Vs[1][d * 64 + phys * 8];
            }
        #pragma unroll
        for (int mt = 0; mt < 4; ++mt)
            #pragma unroll
            for (int nt = 0; nt < 2; ++nt)
                #pragma unroll
                for (int ks = 0; ks < 2; ++ks) {
                    ctx[mt][nt] = __builtin_amdgcn_mfma_f32_16x16x32_bf16(pf[mt][ks], vfh[nt][ks], ctx[mt][nt], 0, 0, 0);
                    ctx[mt][nt] = __builtin_amdgcn_mfma_f32_16x16x32_bf16(pf[mt][ks], vfl[nt][ks], ctx[mt][nt], 0, 0, 0);
                }
    }

    // ---- finalize l (in-quad + cross-wave sum), normalize, store ctx hi/lo ----
    #pragma unroll
    for (int mt = 0; mt < 4; ++mt)
        #pragma unroll
        for (int r = 0; r < 4; ++r) {
            float v = l_cur[mt][r];
            v += __shfl_xor(v, 1);
            v += __shfl_xor(v, 2);
            v += __shfl_xor(v, 4);
            v += __shfl_xor(v, 8);
            if (l15 == 0) red[wr * 64 + mt * 16 + q * 4 + r][wc] = v;
        }
    __syncthreads();
    #pragma unroll
    for (int mt = 0; mt < 4; ++mt)
        #pragma unroll
        for (int r = 0; r < 4; ++r) {
            const int row = wr * 64 + mt * 16 + q * 4 + r;
            const float2 rd = *(const float2*)&red[row][0];
            const float inv = 1.0f / (rd.x + rd.y);
            const int trow = mt * 16 + q * 4 + r;
            #pragma unroll
            for (int nt = 0; nt < 2; ++nt) {
                const int col = wc * 32 + nt * 16 + l15;
                unsigned short hh, ll;
                split_f32(ctx[mt][nt][r] * inv, hh, ll);
                Ctx[qtile + trow * 64 + col] = hh;
                Ctx[qtile + 4096 + trow * 64 + col] = ll;
            }
        }
}

extern "C" void kernel_launch(void* const* d_in, const int* in_sizes, int n_in,
                              void* d_out, int out_size, void* d_ws, size_t ws_size,
                              hipStream_t stream) {
    const float* X  = (const float*)d_in[0];
    const float* Wq = (const float*)d_in[1]; const float* bq = (const float*)d_in[2];
    const float* Wk = (const float*)d_in[3]; const float* bk = (const float*)d_in[4];
    const float* Wv = (const float*)d_in[5]; const float* bv = (const float*)d_in[6];
    const float* Wo = (const float*)d_in[7]; const float* bo = (const float*)d_in[8];

    unsigned short* wsu = (unsigned short*)d_ws;
    unsigned short* Qt  = wsu;                    // 25,165,824 shorts (tiles; ctx in-place)
    unsigned short* KhP = wsu + 25165824L;        // 12,582,912 each
    unsigned short* KlP = KhP + 12582912L;
    unsigned short* VhP = KlP + 12582912L;
    unsigned short* VlP = VhP + 12582912L;
    unsigned short* Wt  = VlP + 12582912L;        // 8 planes x 589,824
    const long WP = (long)H_DIM * H_DIM;
    unsigned short* WqH = Wt;          unsigned short* WqL = Wt + WP;
    unsigned short* WkH = Wt + 2 * WP; unsigned short* WkL = Wt + 3 * WP;
    unsigned short* WvH = Wt + 4 * WP; unsigned short* WvL = Wt + 5 * WP;
    unsigned short* WoH = Wt + 6 * WP; unsigned short* WoL = Wt + 7 * WP;

    // X splits live in d_out (dead until the final projection overwrites it)
    unsigned short* Xhi = (unsigned short*)d_out;
    unsigned short* Xlo = Xhi + SZT;

    prep_x<<<(int)(SZT / 2048), 256, 0, stream>>>(X, Xhi, Xlo);
    dim3 wgrid(12, 12);
    prep_w<<<wgrid, 256, 0, stream>>>(Wq, WqH, WqL);
    prep_w<<<wgrid, 256, 0, stream>>>(Wk, WkH, WkL);
    prep_w<<<wgrid, 256, 0, stream>>>(Wv, WvH, WvL);
    prep_w<<<wgrid, 256, 0, stream>>>(Wo, WoH, WoL);

    const float qscale = 0.125f * 1.4426950408889634f;   // softmax in base-2 domain
    dim3 ggrid(6, 128);
    gemm3<3><<<ggrid, 256, 0, stream>>>(Xhi, Xlo, WqH, WqL, bq, qscale, nullptr, Qt, nullptr);
    gemm3<0><<<ggrid, 256, 0, stream>>>(Xhi, Xlo, WkH, WkL, bk, 1.0f, nullptr, KhP, KlP);
    gemm3<2><<<ggrid, 256, 0, stream>>>(Xhi, Xlo, WvH, WvL, bv, 1.0f, nullptr, VhP, VlP);

    attn_mfma<<<dim3(384, 4), 256, 0, stream>>>(Qt, KhP, KlP, VhP, VlP, Qt);

    gemm3<1><<<ggrid, 256, 0, stream>>>(Qt, Qt + 4096, WoH, WoL, bo, 1.0f,
                                        (float*)d_out, nullptr, nullptr);
}

// Round 4
// 474.460 us; speedup vs baseline: 3.1797x; 1.2382x over previous
//
#include <hip/hip_runtime.h>
#include <cstdint>
#include <cstddef>

#define H_DIM 768
#define NHEADS 12
#define HSZ 64
#define PATCH 512
#define MTOT 16384                 // 8*4*512 tokens
#define SZT ((long)MTOT * H_DIM)   // elements per [16384,768] matrix

using short8 = __attribute__((ext_vector_type(8))) short;   // 8 bf16 (4 VGPRs)
using f32x4  = __attribute__((ext_vector_type(4))) float;   // MFMA accumulator
using us4    = __attribute__((ext_vector_type(4))) unsigned short;

// async global->LDS, 16B per lane; LDS dest = wave-uniform base + lane*16
#define GLL16(gp, lp) __builtin_amdgcn_global_load_lds( \
    (const __attribute__((address_space(1))) void*)(gp), \
    (__attribute__((address_space(3))) void*)(lp), 16, 0, 0)

// fp32 -> bf16 hi (truncate) + bf16 lo (RNE of remainder); hi+lo ~ 2^-17 rel err
__device__ __forceinline__ void split_f32(float x, unsigned short& h, unsigned short& l) {
    unsigned u = __float_as_uint(x);
    h = (unsigned short)(u >> 16);
    float rem = __uint_as_float(u & 0xffff0000u);
    float r = x - rem;                       // exact
    unsigned v = __float_as_uint(r);
    v += 0x7fff + ((v >> 16) & 1);           // RNE to bf16
    l = (unsigned short)(v >> 16);
}

__device__ __forceinline__ unsigned short bf16rne(float x) {
    unsigned v = __float_as_uint(x);
    v += 0x7fff + ((v >> 16) & 1);
    return (unsigned short)(v >> 16);
}

// ------------------------------------------------------------------
// prep_x: X fp32 [16384][768] -> Xhi, Xlo bf16 row-major (stored in d_out)
// ------------------------------------------------------------------
__global__ __launch_bounds__(256) void prep_x(const float* __restrict__ X,
                                              unsigned short* __restrict__ Xhi,
                                              unsigned short* __restrict__ Xlo)
{
    const long i = ((long)blockIdx.x * 256 + threadIdx.x) * 8;
    float4 a = *(const float4*)&X[i];
    float4 b = *(const float4*)&X[i + 4];
    float xs[8] = {a.x, a.y, a.z, a.w, b.x, b.y, b.z, b.w};
    unsigned short h[8], l[8];
    #pragma unroll
    for (int j = 0; j < 8; ++j) split_f32(xs[j], h[j], l[j]);
    us4 h0, h1, l0, l1;
    #pragma unroll
    for (int j = 0; j < 4; ++j) { h0[j] = h[j]; h1[j] = h[j+4]; l0[j] = l[j]; l1[j] = l[j+4]; }
    *(us4*)&Xhi[i] = h0; *(us4*)&Xhi[i + 4] = h1;
    *(us4*)&Xlo[i] = l0; *(us4*)&Xlo[i + 4] = l1;
}

// ------------------------------------------------------------------
// prep_w: W fp32 [k][n] -> transposed split Whi/Wlo bf16 [n][k]
// ------------------------------------------------------------------
__global__ __launch_bounds__(256) void prep_w(const float* __restrict__ W,
                                              unsigned short* __restrict__ Whi,
                                              unsigned short* __restrict__ Wlo)
{
    __shared__ float T[64][65];
    const int kt = blockIdx.x * 64, nt = blockIdx.y * 64;
    const int tid = threadIdx.x;
    const int r = tid >> 2, c16 = (tid & 3) * 16;
    #pragma unroll
    for (int j = 0; j < 4; ++j) {
        float4 v = *(const float4*)&W[(long)(kt + r) * H_DIM + nt + c16 + j * 4];
        T[r][c16 + j*4 + 0] = v.x; T[r][c16 + j*4 + 1] = v.y;
        T[r][c16 + j*4 + 2] = v.z; T[r][c16 + j*4 + 3] = v.w;
    }
    __syncthreads();
    unsigned short* ph = &Whi[(long)(nt + r) * H_DIM + kt + c16];
    unsigned short* pl = &Wlo[(long)(nt + r) * H_DIM + kt + c16];
    #pragma unroll
    for (int j = 0; j < 16; ++j) {
        unsigned short hh, ll;
        split_f32(T[c16 + j][r], hh, ll);
        ph[j] = hh; pl[j] = ll;
    }
}

// ------------------------------------------------------------------
// qkv_gemm: fused Q/K/V projection, bf16x3 (fp32-equivalent) MFMA.
// grid (18, 128): mat = bx/6 selects {Q,K,V}; 128x128 tile, BK=32, 4 waves.
// Epilogues (all single-value bf16 except Q which keeps hi/lo):
//   mat0: Q tiles [bmh][qt]{hi4096,lo4096}, pre-scaled by 0.125*log2e
//   mat1: K planes [bmh][p][d] bf16
//   mat2: V planes [bmh][d][p] bf16 (transposed)
// ------------------------------------------------------------------
__global__ __launch_bounds__(256, 2) void qkv_gemm(
    const unsigned short* __restrict__ Xhi, const unsigned short* __restrict__ Xlo,
    const unsigned short* __restrict__ WqH, const unsigned short* __restrict__ WqL,
    const unsigned short* __restrict__ WkH, const unsigned short* __restrict__ WkL,
    const unsigned short* __restrict__ WvH, const unsigned short* __restrict__ WvL,
    const float* __restrict__ bq, const float* __restrict__ bk, const float* __restrict__ bv,
    float qscale,
    unsigned short* __restrict__ Qt, unsigned short* __restrict__ Kp,
    unsigned short* __restrict__ Vp)
{
    __shared__ unsigned short As[2][4096];
    __shared__ unsigned short Bs[2][4096];

    const int mat = blockIdx.x / 6;
    const int n0  = (blockIdx.x % 6) * 128;
    const int m0  = blockIdx.y * 128;
    const unsigned short* Bh = (mat == 0) ? WqH : (mat == 1) ? WkH : WvH;
    const unsigned short* Bl = (mat == 0) ? WqL : (mat == 1) ? WkL : WvL;
    const float* bias        = (mat == 0) ? bq  : (mat == 1) ? bk  : bv;
    const float scale        = (mat == 0) ? qscale : 1.0f;

    const int tid  = threadIdx.x;
    const int lane = tid & 63;
    const int wv   = tid >> 6;
    const int wr   = wv >> 1, wc = wv & 1;
    const int q    = lane >> 4, l15 = lane & 15;

    const int sRow = tid >> 2;
    const int sKg  = tid & 3;

    char* ldsA = (char*)(&As[0][0]) + (wv << 10);
    char* ldsB = (char*)(&Bs[0][0]) + (wv << 10);

    const int aOff0 = (m0 + sRow) * H_DIM + sKg * 8;
    const int aOff1 = (m0 + 64 + sRow) * H_DIM + sKg * 8;
    const int bOff0 = (n0 + sRow) * H_DIM + sKg * 8;
    const int bOff1 = (n0 + 64 + sRow) * H_DIM + sKg * 8;

    f32x4 acc[4][4];
    #pragma unroll
    for (int i = 0; i < 4; ++i)
        #pragma unroll
        for (int j = 0; j < 4; ++j) acc[i][j] = 0;

    for (int k0 = 0; k0 < H_DIM; k0 += 32) {
        GLL16(Xhi + aOff0 + k0, ldsA);
        GLL16(Xhi + aOff1 + k0, ldsA + 4096);
        GLL16(Xlo + aOff0 + k0, ldsA + 8192);
        GLL16(Xlo + aOff1 + k0, ldsA + 12288);
        GLL16(Bh + bOff0 + k0, ldsB);
        GLL16(Bh + bOff1 + k0, ldsB + 4096);
        GLL16(Bl + bOff0 + k0, ldsB + 8192);
        GLL16(Bl + bOff1 + k0, ldsB + 12288);
        __syncthreads();

        short8 ah[4], al[4], bh[4], bl[4];
        #pragma unroll
        for (int t = 0; t < 4; ++t) {
            const int mr = wr * 64 + t * 16 + l15;
            ah[t] = *(const short8*)&As[0][mr * 32 + q * 8];
            al[t] = *(const short8*)&As[1][mr * 32 + q * 8];
            const int nr = wc * 64 + t * 16 + l15;
            bh[t] = *(const short8*)&Bs[0][nr * 32 + q * 8];
            bl[t] = *(const short8*)&Bs[1][nr * 32 + q * 8];
        }
        #pragma unroll
        for (int mt = 0; mt < 4; ++mt)
            #pragma unroll
            for (int nt = 0; nt < 4; ++nt) {
                acc[mt][nt] = __builtin_amdgcn_mfma_f32_16x16x32_bf16(ah[mt], bh[nt], acc[mt][nt], 0, 0, 0);
                acc[mt][nt] = __builtin_amdgcn_mfma_f32_16x16x32_bf16(ah[mt], bl[nt], acc[mt][nt], 0, 0, 0);
                acc[mt][nt] = __builtin_amdgcn_mfma_f32_16x16x32_bf16(al[mt], bh[nt], acc[mt][nt], 0, 0, 0);
            }
        __syncthreads();
    }

    // epilogue: C/D layout col = lane&15, row = quad*4 + reg
    #pragma unroll
    for (int nt = 0; nt < 4; ++nt) {
        const int col = n0 + wc * 64 + nt * 16 + l15;
        const float bcol = bias[col];
        const int h = col >> 6, d = col & 63;
        #pragma unroll
        for (int mt = 0; mt < 4; ++mt) {
            const int rowB = m0 + wr * 64 + mt * 16 + q * 4;
            #pragma unroll
            for (int r = 0; r < 4; ++r) {
                const int row = rowB + r;
                const float val = (acc[mt][nt][r] + bcol) * scale;
                const int bm = row >> 9, p = row & 511;
                const int bmh = bm * NHEADS + h;
                if (mat == 0) {
                    unsigned short hh, ll;
                    split_f32(val, hh, ll);
                    const long idx = ((long)bmh * 8 + (p >> 6)) * 8192 + (long)(p & 63) * 64 + d;
                    Qt[idx] = hh; Qt[idx + 4096] = ll;
                } else if (mat == 1) {
                    Kp[(long)bmh * 32768 + (long)p * 64 + d] = bf16rne(val);
                } else {
                    Vp[(long)bmh * 32768 + (long)d * 512 + p] = bf16rne(val);
                }
            }
        }
    }
}

// ------------------------------------------------------------------
// attn2: flash attention without max-tracking (scores bounded; softmax
// in base-2, Q pre-scaled by 0.125*log2e). QK 2-pass (Q hi/lo x K bf16),
// PV 1-pass (P bf16 x V bf16). 128 q-rows/block, 64-key tiles, 8 iters.
// ctx bf16 written in place over the block's own Q tiles (plane 0).
// ------------------------------------------------------------------
__global__ __launch_bounds__(256, 3) void attn2(
    const unsigned short* __restrict__ Qt,
    const unsigned short* __restrict__ Kp, const unsigned short* __restrict__ Vp,
    unsigned short* __restrict__ Ctx)
{
    __shared__ unsigned short Ks[4096];      // [key][swz-chunk*8] bf16
    __shared__ unsigned short Vs[4096];      // [d][swz-chunk*8] bf16
    __shared__ unsigned short Ps[128 * 72];  // P bf16, padded stride 72
    __shared__ float red[128][2];            // cross-wave row sum (finalize)

    const int tid  = threadIdx.x;
    const int lane = tid & 63;
    const int wv   = tid >> 6;
    const int wr   = wv >> 1, wc = wv & 1;
    const int q    = lane >> 4, l15 = lane & 15;
    const int qt2  = blockIdx.x;     // 0..3
    const int bmh  = blockIdx.y;     // 0..383

    // ---- Q fragments (hi/lo, loop-invariant) ----
    short8 qh[4][2], ql[4][2];
    const long qtile = ((long)bmh * 8 + qt2 * 2 + wr) * 8192;
    #pragma unroll
    for (int mt = 0; mt < 4; ++mt)
        #pragma unroll
        for (int ks = 0; ks < 2; ++ks) {
            const long o = qtile + (mt * 16 + l15) * 64 + ks * 32 + q * 8;
            qh[mt][ks] = *(const short8*)&Qt[o];
            ql[mt][ks] = *(const short8*)&Qt[o + 4096];
        }

    f32x4 ctx[4][2];
    float l_cur[4][4];
    #pragma unroll
    for (int mt = 0; mt < 4; ++mt) {
        ctx[mt][0] = 0; ctx[mt][1] = 0;
        #pragma unroll
        for (int r = 0; r < 4; ++r) l_cur[mt][r] = 0.0f;
    }

    const long khead = (long)bmh * 32768;
    const int srow   = tid >> 3;                               // 0..31
    const int gchunk = ((tid & 7) ^ (srow & 7)) * 8;           // swizzled source chunk
    char* dK = (char*)&Ks[0] + (wv << 10);
    char* dV = (char*)&Vs[0] + (wv << 10);

    for (int kt = 0; kt < 8; ++kt) {
        __syncthreads();   // prev iter's QK/PV reads of Ks/Vs/Ps complete
        {
            const long kb = khead + (long)kt * 64 * 64;
            GLL16(Kp + kb + (long)srow * 64 + gchunk,        dK);
            GLL16(Kp + kb + (long)(srow + 32) * 64 + gchunk, dK + 4096);
            const long vb = khead + (long)kt * 64;
            GLL16(Vp + vb + (long)srow * 512 + gchunk,        dV);
            GLL16(Vp + vb + (long)(srow + 32) * 512 + gchunk, dV + 4096);
        }
        __syncthreads();   // staging landed (barrier drains vmcnt)

        // ---- S = Q K^T (2-pass) : rows wr*64+, keys wc*32+ ----
        f32x4 s[4][2];
        #pragma unroll
        for (int mt = 0; mt < 4; ++mt) { s[mt][0] = 0; s[mt][1] = 0; }
        short8 kf[2][2];
        #pragma unroll
        for (int nt = 0; nt < 2; ++nt)
            #pragma unroll
            for (int ks = 0; ks < 2; ++ks) {
                const int key = wc * 32 + nt * 16 + l15;
                const int phys = (q + ks * 4) ^ (key & 7);
                kf[nt][ks] = *(const short8*)&Ks[key * 64 + phys * 8];
            }
        #pragma unroll
        for (int mt = 0; mt < 4; ++mt)
            #pragma unroll
            for (int nt = 0; nt < 2; ++nt)
                #pragma unroll
                for (int ks = 0; ks < 2; ++ks) {
                    s[mt][nt] = __builtin_amdgcn_mfma_f32_16x16x32_bf16(qh[mt][ks], kf[nt][ks], s[mt][nt], 0, 0, 0);
                    s[mt][nt] = __builtin_amdgcn_mfma_f32_16x16x32_bf16(ql[mt][ks], kf[nt][ks], s[mt][nt], 0, 0, 0);
                }

        // ---- p = exp2(s); accumulate l; write P bf16 ----
        #pragma unroll
        for (int mt = 0; mt < 4; ++mt)
            #pragma unroll
            for (int r = 0; r < 4; ++r) {
                const int row = wr * 64 + mt * 16 + q * 4 + r;
                const float p0 = __builtin_amdgcn_exp2f(s[mt][0][r]);
                const float p1 = __builtin_amdgcn_exp2f(s[mt][1][r]);
                l_cur[mt][r] += p0 + p1;
                Ps[row * 72 + wc * 32 + l15]      = bf16rne(p0);
                Ps[row * 72 + wc * 32 + 16 + l15] = bf16rne(p1);
            }
        __syncthreads();

        // ---- ctx += P V (1-pass) : rows wr*64+, d-cols wc*32+ ----
        short8 pf[4][2], vf[2][2];
        #pragma unroll
        for (int mt = 0; mt < 4; ++mt)
            #pragma unroll
            for (int ks = 0; ks < 2; ++ks)
                pf[mt][ks] = *(const short8*)&Ps[(wr * 64 + mt * 16 + l15) * 72 + ks * 32 + q * 8];
        #pragma unroll
        for (int nt = 0; nt < 2; ++nt)
            #pragma unroll
            for (int ks = 0; ks < 2; ++ks) {
                const int d = wc * 32 + nt * 16 + l15;
                const int phys = (q + ks * 4) ^ (d & 7);
                vf[nt][ks] = *(const short8*)&Vs[d * 64 + phys * 8];
            }
        #pragma unroll
        for (int mt = 0; mt < 4; ++mt)
            #pragma unroll
            for (int nt = 0; nt < 2; ++nt)
                #pragma unroll
                for (int ks = 0; ks < 2; ++ks)
                    ctx[mt][nt] = __builtin_amdgcn_mfma_f32_16x16x32_bf16(pf[mt][ks], vf[nt][ks], ctx[mt][nt], 0, 0, 0);
    }

    // ---- finalize l (in-quad + cross-wave sum), normalize, store ctx bf16 ----
    #pragma unroll
    for (int mt = 0; mt < 4; ++mt)
        #pragma unroll
        for (int r = 0; r < 4; ++r) {
            float v = l_cur[mt][r];
            v += __shfl_xor(v, 1);
            v += __shfl_xor(v, 2);
            v += __shfl_xor(v, 4);
            v += __shfl_xor(v, 8);
            if (l15 == 0) red[wr * 64 + mt * 16 + q * 4 + r][wc] = v;
        }
    __syncthreads();
    #pragma unroll
    for (int mt = 0; mt < 4; ++mt)
        #pragma unroll
        for (int r = 0; r < 4; ++r) {
            const int row = wr * 64 + mt * 16 + q * 4 + r;
            const float2 rd = *(const float2*)&red[row][0];
            const float inv = 1.0f / (rd.x + rd.y);
            const int trow = mt * 16 + q * 4 + r;
            #pragma unroll
            for (int nt = 0; nt < 2; ++nt) {
                const int col = wc * 32 + nt * 16 + l15;
                Ctx[qtile + trow * 64 + col] = bf16rne(ctx[mt][nt][r] * inv);
            }
        }
}

// ------------------------------------------------------------------
// oproj: Out = ctx @ Wo + bo, 2-pass MFMA (ctx bf16 x Wo hi/lo).
// A read from ctx tiles (stride 8192, plane 0). Out fp32 row-major.
// ------------------------------------------------------------------
__global__ __launch_bounds__(256, 2) void oproj(
    const unsigned short* __restrict__ Ctx,
    const unsigned short* __restrict__ WoH, const unsigned short* __restrict__ WoL,
    const float* __restrict__ bo, float* __restrict__ out)
{
    __shared__ unsigned short As[4096];
    __shared__ unsigned short Bs[2][4096];

    const int tid  = threadIdx.x;
    const int lane = tid & 63;
    const int wv   = tid >> 6;
    const int wr   = wv >> 1, wc = wv & 1;
    const int q    = lane >> 4, l15 = lane & 15;
    const int m0   = blockIdx.y * 128;
    const int n0   = blockIdx.x * 128;

    const int sRow = tid >> 2;
    const int sKg  = tid & 3;

    char* ldsA = (char*)(&As[0]) + (wv << 10);
    char* ldsB = (char*)(&Bs[0][0]) + (wv << 10);

    const int bOff0 = (n0 + sRow) * H_DIM + sKg * 8;
    const int bOff1 = (n0 + 64 + sRow) * H_DIM + sKg * 8;

    f32x4 acc[4][4];
    #pragma unroll
    for (int i = 0; i < 4; ++i)
        #pragma unroll
        for (int j = 0; j < 4; ++j) acc[i][j] = 0;

    for (int k0 = 0; k0 < H_DIM; k0 += 32) {
        const int h = k0 >> 6;
        const int d = (k0 & 63) + sKg * 8;
        const int tok0 = m0 + sRow, tok1 = m0 + 64 + sRow;
        const long t0 = (((long)(tok0 >> 9) * NHEADS + h) * 8 + ((tok0 >> 6) & 7)) * 8192
                      + (long)(tok0 & 63) * 64 + d;
        const long t1 = (((long)(tok1 >> 9) * NHEADS + h) * 8 + ((tok1 >> 6) & 7)) * 8192
                      + (long)(tok1 & 63) * 64 + d;
        GLL16(Ctx + t0, ldsA);
        GLL16(Ctx + t1, ldsA + 4096);
        GLL16(WoH + bOff0 + k0, ldsB);
        GLL16(WoH + bOff1 + k0, ldsB + 4096);
        GLL16(WoL + bOff0 + k0, ldsB + 8192);
        GLL16(WoL + bOff1 + k0, ldsB + 12288);
        __syncthreads();

        short8 ah[4], bh[4], bl[4];
        #pragma unroll
        for (int t = 0; t < 4; ++t) {
            const int mr = wr * 64 + t * 16 + l15;
            ah[t] = *(const short8*)&As[mr * 32 + q * 8];
            const int nr = wc * 64 + t * 16 + l15;
            bh[t] = *(const short8*)&Bs[0][nr * 32 + q * 8];
            bl[t] = *(const short8*)&Bs[1][nr * 32 + q * 8];
        }
        #pragma unroll
        for (int mt = 0; mt < 4; ++mt)
            #pragma unroll
            for (int nt = 0; nt < 4; ++nt) {
                acc[mt][nt] = __builtin_amdgcn_mfma_f32_16x16x32_bf16(ah[mt], bh[nt], acc[mt][nt], 0, 0, 0);
                acc[mt][nt] = __builtin_amdgcn_mfma_f32_16x16x32_bf16(ah[mt], bl[nt], acc[mt][nt], 0, 0, 0);
            }
        __syncthreads();
    }

    #pragma unroll
    for (int nt = 0; nt < 4; ++nt) {
        const int col = n0 + wc * 64 + nt * 16 + l15;
        const float bcol = bo[col];
        #pragma unroll
        for (int mt = 0; mt < 4; ++mt) {
            const int rowB = m0 + wr * 64 + mt * 16 + q * 4;
            #pragma unroll
            for (int r = 0; r < 4; ++r)
                out[(long)(rowB + r) * H_DIM + col] = acc[mt][nt][r] + bcol;
        }
    }
}

extern "C" void kernel_launch(void* const* d_in, const int* in_sizes, int n_in,
                              void* d_out, int out_size, void* d_ws, size_t ws_size,
                              hipStream_t stream) {
    const float* X  = (const float*)d_in[0];
    const float* Wq = (const float*)d_in[1]; const float* bq = (const float*)d_in[2];
    const float* Wk = (const float*)d_in[3]; const float* bk = (const float*)d_in[4];
    const float* Wv = (const float*)d_in[5]; const float* bv = (const float*)d_in[6];
    const float* Wo = (const float*)d_in[7]; const float* bo = (const float*)d_in[8];

    unsigned short* wsu = (unsigned short*)d_ws;
    unsigned short* Qt  = wsu;                    // 25,165,824 shorts (Q hi/lo tiles; ctx in place)
    unsigned short* Kp  = wsu + 25165824L;        // 12,582,912 (bf16 [bmh][p][d])
    unsigned short* Vp  = Kp + 12582912L;         // 12,582,912 (bf16 [bmh][d][p])
    unsigned short* Wt  = Vp + 12582912L;         // 8 planes x 589,824
    const long WP = (long)H_DIM * H_DIM;
    unsigned short* WqH = Wt;          unsigned short* WqL = Wt + WP;
    unsigned short* WkH = Wt + 2 * WP; unsigned short* WkL = Wt + 3 * WP;
    unsigned short* WvH = Wt + 4 * WP; unsigned short* WvL = Wt + 5 * WP;
    unsigned short* WoH = Wt + 6 * WP; unsigned short* WoL = Wt + 7 * WP;

    // X splits live in d_out (dead until oproj overwrites it)
    unsigned short* Xhi = (unsigned short*)d_out;
    unsigned short* Xlo = Xhi + SZT;

    prep_x<<<(int)(SZT / 2048), 256, 0, stream>>>(X, Xhi, Xlo);
    dim3 wgrid(12, 12);
    prep_w<<<wgrid, 256, 0, stream>>>(Wq, WqH, WqL);
    prep_w<<<wgrid, 256, 0, stream>>>(Wk, WkH, WkL);
    prep_w<<<wgrid, 256, 0, stream>>>(Wv, WvH, WvL);
    prep_w<<<wgrid, 256, 0, stream>>>(Wo, WoH, WoL);

    const float qscale = 0.125f * 1.4426950408889634f;   // softmax in base-2 domain
    qkv_gemm<<<dim3(18, 128), 256, 0, stream>>>(Xhi, Xlo, WqH, WqL, WkH, WkL, WvH, WvL,
                                                bq, bk, bv, qscale, Qt, Kp, Vp);

    attn2<<<dim3(4, 384), 256, 0, stream>>>(Qt, Kp, Vp, Qt);

    oproj<<<dim3(6, 128), 256, 0, stream>>>(Qt, WoH, WoL, bo, (float*)d_out);
}

// Round 5
// 400.560 us; speedup vs baseline: 3.7663x; 1.1845x over previous
//
#include <hip/hip_runtime.h>
#include <cstdint>
#include <cstddef>

#define H_DIM 768
#define NHEADS 12
#define HSZ 64
#define PATCH 512
#define MTOT 16384                 // 8*4*512 tokens
#define SZT ((long)MTOT * H_DIM)   // elements per [16384,768] matrix

using short8 = __attribute__((ext_vector_type(8))) short;   // 8 bf16 (4 VGPRs)
using f32x4  = __attribute__((ext_vector_type(4))) float;   // MFMA accumulator
using us4    = __attribute__((ext_vector_type(4))) unsigned short;

// async global->LDS, 16B per lane; LDS dest = wave-uniform base + lane*16
#define GLL16(gp, lp) __builtin_amdgcn_global_load_lds( \
    (const __attribute__((address_space(1))) void*)(gp), \
    (__attribute__((address_space(3))) void*)(lp), 16, 0, 0)

// fp32 -> bf16 hi (truncate) + bf16 lo (RNE of remainder); hi+lo ~ 2^-17 rel err
__device__ __forceinline__ void split_f32(float x, unsigned short& h, unsigned short& l) {
    unsigned u = __float_as_uint(x);
    h = (unsigned short)(u >> 16);
    float rem = __uint_as_float(u & 0xffff0000u);
    float r = x - rem;                       // exact
    unsigned v = __float_as_uint(r);
    v += 0x7fff + ((v >> 16) & 1);           // RNE to bf16
    l = (unsigned short)(v >> 16);
}

__device__ __forceinline__ unsigned short bf16rne(float x) {
    unsigned v = __float_as_uint(x);
    v += 0x7fff + ((v >> 16) & 1);
    return (unsigned short)(v >> 16);
}

// ------------------------------------------------------------------
// prep_x: X fp32 [16384][768] -> X~ bf16 RNE row-major (stored in d_out)
// ------------------------------------------------------------------
__global__ __launch_bounds__(256) void prep_x(const float* __restrict__ X,
                                              unsigned short* __restrict__ Xb)
{
    const long i = ((long)blockIdx.x * 256 + threadIdx.x) * 8;
    float4 a = *(const float4*)&X[i];
    float4 b = *(const float4*)&X[i + 4];
    float xs[8] = {a.x, a.y, a.z, a.w, b.x, b.y, b.z, b.w};
    us4 h0, h1;
    #pragma unroll
    for (int j = 0; j < 4; ++j) { h0[j] = bf16rne(xs[j]); h1[j] = bf16rne(xs[j + 4]); }
    *(us4*)&Xb[i] = h0; *(us4*)&Xb[i + 4] = h1;
}

// ------------------------------------------------------------------
// prep_w: W fp32 [k][n] -> transposed split Whi/Wlo bf16 [n][k]
// ------------------------------------------------------------------
__global__ __launch_bounds__(256) void prep_w(const float* __restrict__ W,
                                              unsigned short* __restrict__ Whi,
                                              unsigned short* __restrict__ Wlo)
{
    __shared__ float T[64][65];
    const int kt = blockIdx.x * 64, nt = blockIdx.y * 64;
    const int tid = threadIdx.x;
    const int r = tid >> 2, c16 = (tid & 3) * 16;
    #pragma unroll
    for (int j = 0; j < 4; ++j) {
        float4 v = *(const float4*)&W[(long)(kt + r) * H_DIM + nt + c16 + j * 4];
        T[r][c16 + j*4 + 0] = v.x; T[r][c16 + j*4 + 1] = v.y;
        T[r][c16 + j*4 + 2] = v.z; T[r][c16 + j*4 + 3] = v.w;
    }
    __syncthreads();
    unsigned short* ph = &Whi[(long)(nt + r) * H_DIM + kt + c16];
    unsigned short* pl = &Wlo[(long)(nt + r) * H_DIM + kt + c16];
    #pragma unroll
    for (int j = 0; j < 16; ++j) {
        unsigned short hh, ll;
        split_f32(T[c16 + j][r], hh, ll);
        ph[j] = hh; pl[j] = ll;
    }
}

// ------------------------------------------------------------------
// qkv_gemm: fused Q/K/V projection, 2-pass MFMA (X~ bf16 x W hi/lo).
// grid (18, 128): mat = bx/6 selects {Q,K,V}; 128x128 tile, BK=32, 4 waves.
// LDS XOR-swizzle: staged chunk kg ^ ((row>>1)&3) -> 2-way bank access (free).
// Epilogues: mat0 Q tiles hi/lo (pre-scaled), mat1 K planes [p][d],
//            mat2 V planes [d][p] (transposed); K/V single bf16.
// ------------------------------------------------------------------
__global__ __launch_bounds__(256, 3) void qkv_gemm(
    const unsigned short* __restrict__ Xb,
    const unsigned short* __restrict__ WqH, const unsigned short* __restrict__ WqL,
    const unsigned short* __restrict__ WkH, const unsigned short* __restrict__ WkL,
    const unsigned short* __restrict__ WvH, const unsigned short* __restrict__ WvL,
    const float* __restrict__ bq, const float* __restrict__ bk, const float* __restrict__ bv,
    float qscale,
    unsigned short* __restrict__ Qt, unsigned short* __restrict__ Kp,
    unsigned short* __restrict__ Vp)
{
    __shared__ unsigned short As[4096];      // X~ tile: 128 rows x 32 k (swizzled chunks)
    __shared__ unsigned short Bs[2][4096];   // W hi/lo tiles

    const int mat = blockIdx.x / 6;
    const int n0  = (blockIdx.x % 6) * 128;
    const int m0  = blockIdx.y * 128;
    const unsigned short* Bh = (mat == 0) ? WqH : (mat == 1) ? WkH : WvH;
    const unsigned short* Bl = (mat == 0) ? WqL : (mat == 1) ? WkL : WvL;
    const float* bias        = (mat == 0) ? bq  : (mat == 1) ? bk  : bv;
    const float scale        = (mat == 0) ? qscale : 1.0f;

    const int tid  = threadIdx.x;
    const int lane = tid & 63;
    const int wv   = tid >> 6;
    const int wr   = wv >> 1, wc = wv & 1;
    const int q    = lane >> 4, l15 = lane & 15;

    const int sRow = tid >> 2;                          // 0..63
    const int sKg  = (tid & 3) ^ ((sRow >> 1) & 3);     // swizzled source chunk

    char* ldsA = (char*)(&As[0]) + (wv << 10);
    char* ldsB = (char*)(&Bs[0][0]) + (wv << 10);

    const int aOff0 = (m0 + sRow) * H_DIM + sKg * 8;
    const int aOff1 = (m0 + 64 + sRow) * H_DIM + sKg * 8;
    const int bOff0 = (n0 + sRow) * H_DIM + sKg * 8;
    const int bOff1 = (n0 + 64 + sRow) * H_DIM + sKg * 8;

    f32x4 acc[4][4];
    #pragma unroll
    for (int i = 0; i < 4; ++i)
        #pragma unroll
        for (int j = 0; j < 4; ++j) acc[i][j] = 0;

    for (int k0 = 0; k0 < H_DIM; k0 += 32) {
        GLL16(Xb + aOff0 + k0, ldsA);
        GLL16(Xb + aOff1 + k0, ldsA + 4096);
        GLL16(Bh + bOff0 + k0, ldsB);
        GLL16(Bh + bOff1 + k0, ldsB + 4096);
        GLL16(Bl + bOff0 + k0, ldsB + 8192);
        GLL16(Bl + bOff1 + k0, ldsB + 12288);
        __syncthreads();

        short8 ah[4], bh[4], bl[4];
        #pragma unroll
        for (int t = 0; t < 4; ++t) {
            const int mr = wr * 64 + t * 16 + l15;
            const int pa = (q ^ ((mr >> 1) & 3)) * 8;
            ah[t] = *(const short8*)&As[mr * 32 + pa];
            const int nr = wc * 64 + t * 16 + l15;
            const int pb = (q ^ ((nr >> 1) & 3)) * 8;
            bh[t] = *(const short8*)&Bs[0][nr * 32 + pb];
            bl[t] = *(const short8*)&Bs[1][nr * 32 + pb];
        }
        #pragma unroll
        for (int mt = 0; mt < 4; ++mt)
            #pragma unroll
            for (int nt = 0; nt < 4; ++nt) {
                acc[mt][nt] = __builtin_amdgcn_mfma_f32_16x16x32_bf16(ah[mt], bh[nt], acc[mt][nt], 0, 0, 0);
                acc[mt][nt] = __builtin_amdgcn_mfma_f32_16x16x32_bf16(ah[mt], bl[nt], acc[mt][nt], 0, 0, 0);
            }
        __syncthreads();
    }

    // epilogue: C/D layout col = lane&15, row = quad*4 + reg
    #pragma unroll
    for (int nt = 0; nt < 4; ++nt) {
        const int col = n0 + wc * 64 + nt * 16 + l15;
        const float bcol = bias[col];
        const int h = col >> 6, d = col & 63;
        #pragma unroll
        for (int mt = 0; mt < 4; ++mt) {
            const int rowB = m0 + wr * 64 + mt * 16 + q * 4;
            #pragma unroll
            for (int r = 0; r < 4; ++r) {
                const int row = rowB + r;
                const float val = (acc[mt][nt][r] + bcol) * scale;
                const int bm = row >> 9, p = row & 511;
                const int bmh = bm * NHEADS + h;
                if (mat == 0) {
                    unsigned short hh, ll;
                    split_f32(val, hh, ll);
                    const long idx = ((long)bmh * 8 + (p >> 6)) * 8192 + (long)(p & 63) * 64 + d;
                    Qt[idx] = hh; Qt[idx + 4096] = ll;
                } else if (mat == 1) {
                    Kp[(long)bmh * 32768 + (long)p * 64 + d] = bf16rne(val);
                } else {
                    Vp[(long)bmh * 32768 + (long)d * 512 + p] = bf16rne(val);
                }
            }
        }
    }
}

// ------------------------------------------------------------------
// attn2: flash attention without max-tracking (scores bounded; softmax
// in base-2, Q pre-scaled by 0.125*log2e). QK 2-pass (Q hi/lo x K bf16),
// PV 1-pass (P bf16 x V bf16). 128 q-rows/block, 64-key tiles, 8 iters.
// ctx bf16 written in place over the block's own Q tiles (plane 0).
// ------------------------------------------------------------------
__global__ __launch_bounds__(256, 3) void attn2(
    const unsigned short* __restrict__ Qt,
    const unsigned short* __restrict__ Kp, const unsigned short* __restrict__ Vp,
    unsigned short* __restrict__ Ctx)
{
    __shared__ unsigned short Ks[4096];      // [key][swz-chunk*8] bf16
    __shared__ unsigned short Vs[4096];      // [d][swz-chunk*8] bf16
    __shared__ unsigned short Ps[128 * 72];  // P bf16, padded stride 72
    __shared__ float red[128][2];            // cross-wave row sum (finalize)

    const int tid  = threadIdx.x;
    const int lane = tid & 63;
    const int wv   = tid >> 6;
    const int wr   = wv >> 1, wc = wv & 1;
    const int q    = lane >> 4, l15 = lane & 15;
    const int qt2  = blockIdx.x;     // 0..3
    const int bmh  = blockIdx.y;     // 0..383

    // ---- Q fragments (hi/lo, loop-invariant) ----
    short8 qh[4][2], ql[4][2];
    const long qtile = ((long)bmh * 8 + qt2 * 2 + wr) * 8192;
    #pragma unroll
    for (int mt = 0; mt < 4; ++mt)
        #pragma unroll
        for (int ks = 0; ks < 2; ++ks) {
            const long o = qtile + (mt * 16 + l15) * 64 + ks * 32 + q * 8;
            qh[mt][ks] = *(const short8*)&Qt[o];
            ql[mt][ks] = *(const short8*)&Qt[o + 4096];
        }

    f32x4 ctx[4][2];
    float l_cur[4][4];
    #pragma unroll
    for (int mt = 0; mt < 4; ++mt) {
        ctx[mt][0] = 0; ctx[mt][1] = 0;
        #pragma unroll
        for (int r = 0; r < 4; ++r) l_cur[mt][r] = 0.0f;
    }

    const long khead = (long)bmh * 32768;
    const int srow   = tid >> 3;                               // 0..31
    const int gchunk = ((tid & 7) ^ (srow & 7)) * 8;           // swizzled source chunk
    char* dK = (char*)&Ks[0] + (wv << 10);
    char* dV = (char*)&Vs[0] + (wv << 10);

    for (int kt = 0; kt < 8; ++kt) {
        __syncthreads();   // prev iter's QK/PV reads of Ks/Vs/Ps complete
        {
            const long kb = khead + (long)kt * 64 * 64;
            GLL16(Kp + kb + (long)srow * 64 + gchunk,        dK);
            GLL16(Kp + kb + (long)(srow + 32) * 64 + gchunk, dK + 4096);
            const long vb = khead + (long)kt * 64;
            GLL16(Vp + vb + (long)srow * 512 + gchunk,        dV);
            GLL16(Vp + vb + (long)(srow + 32) * 512 + gchunk, dV + 4096);
        }
        __syncthreads();   // staging landed (barrier drains vmcnt)

        // ---- S = Q K^T (2-pass) : rows wr*64+, keys wc*32+ ----
        f32x4 s[4][2];
        #pragma unroll
        for (int mt = 0; mt < 4; ++mt) { s[mt][0] = 0; s[mt][1] = 0; }
        short8 kf[2][2];
        #pragma unroll
        for (int nt = 0; nt < 2; ++nt)
            #pragma unroll
            for (int ks = 0; ks < 2; ++ks) {
                const int key = wc * 32 + nt * 16 + l15;
                const int phys = (q + ks * 4) ^ (key & 7);
                kf[nt][ks] = *(const short8*)&Ks[key * 64 + phys * 8];
            }
        #pragma unroll
        for (int mt = 0; mt < 4; ++mt)
            #pragma unroll
            for (int nt = 0; nt < 2; ++nt)
                #pragma unroll
                for (int ks = 0; ks < 2; ++ks) {
                    s[mt][nt] = __builtin_amdgcn_mfma_f32_16x16x32_bf16(qh[mt][ks], kf[nt][ks], s[mt][nt], 0, 0, 0);
                    s[mt][nt] = __builtin_amdgcn_mfma_f32_16x16x32_bf16(ql[mt][ks], kf[nt][ks], s[mt][nt], 0, 0, 0);
                }

        // ---- p = exp2(s); accumulate l; write P bf16 ----
        #pragma unroll
        for (int mt = 0; mt < 4; ++mt)
            #pragma unroll
            for (int r = 0; r < 4; ++r) {
                const int row = wr * 64 + mt * 16 + q * 4 + r;
                const float p0 = __builtin_amdgcn_exp2f(s[mt][0][r]);
                const float p1 = __builtin_amdgcn_exp2f(s[mt][1][r]);
                l_cur[mt][r] += p0 + p1;
                Ps[row * 72 + wc * 32 + l15]      = bf16rne(p0);
                Ps[row * 72 + wc * 32 + 16 + l15] = bf16rne(p1);
            }
        __syncthreads();

        // ---- ctx += P V (1-pass) : rows wr*64+, d-cols wc*32+ ----
        short8 pf[4][2], vf[2][2];
        #pragma unroll
        for (int mt = 0; mt < 4; ++mt)
            #pragma unroll
            for (int ks = 0; ks < 2; ++ks)
                pf[mt][ks] = *(const short8*)&Ps[(wr * 64 + mt * 16 + l15) * 72 + ks * 32 + q * 8];
        #pragma unroll
        for (int nt = 0; nt < 2; ++nt)
            #pragma unroll
            for (int ks = 0; ks < 2; ++ks) {
                const int d = wc * 32 + nt * 16 + l15;
                const int phys = (q + ks * 4) ^ (d & 7);
                vf[nt][ks] = *(const short8*)&Vs[d * 64 + phys * 8];
            }
        #pragma unroll
        for (int mt = 0; mt < 4; ++mt)
            #pragma unroll
            for (int nt = 0; nt < 2; ++nt)
                #pragma unroll
                for (int ks = 0; ks < 2; ++ks)
                    ctx[mt][nt] = __builtin_amdgcn_mfma_f32_16x16x32_bf16(pf[mt][ks], vf[nt][ks], ctx[mt][nt], 0, 0, 0);
    }

    // ---- finalize l (in-quad + cross-wave sum), normalize, store ctx bf16 ----
    #pragma unroll
    for (int mt = 0; mt < 4; ++mt)
        #pragma unroll
        for (int r = 0; r < 4; ++r) {
            float v = l_cur[mt][r];
            v += __shfl_xor(v, 1);
            v += __shfl_xor(v, 2);
            v += __shfl_xor(v, 4);
            v += __shfl_xor(v, 8);
            if (l15 == 0) red[wr * 64 + mt * 16 + q * 4 + r][wc] = v;
        }
    __syncthreads();
    #pragma unroll
    for (int mt = 0; mt < 4; ++mt)
        #pragma unroll
        for (int r = 0; r < 4; ++r) {
            const int row = wr * 64 + mt * 16 + q * 4 + r;
            const float2 rd = *(const float2*)&red[row][0];
            const float inv = 1.0f / (rd.x + rd.y);
            const int trow = mt * 16 + q * 4 + r;
            #pragma unroll
            for (int nt = 0; nt < 2; ++nt) {
                const int col = wc * 32 + nt * 16 + l15;
                Ctx[qtile + trow * 64 + col] = bf16rne(ctx[mt][nt][r] * inv);
            }
        }
}

// ------------------------------------------------------------------
// oproj: Out = ctx @ Wo + bo, 2-pass MFMA (ctx bf16 x Wo hi/lo).
// A read from ctx tiles (stride 8192, plane 0). Out fp32 row-major.
// Same LDS XOR swizzle as qkv_gemm.
// ------------------------------------------------------------------
__global__ __launch_bounds__(256, 3) void oproj(
    const unsigned short* __restrict__ Ctx,
    const unsigned short* __restrict__ WoH, const unsigned short* __restrict__ WoL,
    const float* __restrict__ bo, float* __restrict__ out)
{
    __shared__ unsigned short As[4096];
    __shared__ unsigned short Bs[2][4096];

    const int tid  = threadIdx.x;
    const int lane = tid & 63;
    const int wv   = tid >> 6;
    const int wr   = wv >> 1, wc = wv & 1;
    const int q    = lane >> 4, l15 = lane & 15;
    const int m0   = blockIdx.y * 128;
    const int n0   = blockIdx.x * 128;

    const int sRow = tid >> 2;
    const int sKg  = (tid & 3) ^ ((sRow >> 1) & 3);     // swizzled source chunk

    char* ldsA = (char*)(&As[0]) + (wv << 10);
    char* ldsB = (char*)(&Bs[0][0]) + (wv << 10);

    const int bOff0 = (n0 + sRow) * H_DIM + sKg * 8;
    const int bOff1 = (n0 + 64 + sRow) * H_DIM + sKg * 8;

    f32x4 acc[4][4];
    #pragma unroll
    for (int i = 0; i < 4; ++i)
        #pragma unroll
        for (int j = 0; j < 4; ++j) acc[i][j] = 0;

    for (int k0 = 0; k0 < H_DIM; k0 += 32) {
        const int h = k0 >> 6;
        const int d = (k0 & 63) + sKg * 8;
        const int tok0 = m0 + sRow, tok1 = m0 + 64 + sRow;
        const long t0 = (((long)(tok0 >> 9) * NHEADS + h) * 8 + ((tok0 >> 6) & 7)) * 8192
                      + (long)(tok0 & 63) * 64 + d;
        const long t1 = (((long)(tok1 >> 9) * NHEADS + h) * 8 + ((tok1 >> 6) & 7)) * 8192
                      + (long)(tok1 & 63) * 64 + d;
        GLL16(Ctx + t0, ldsA);
        GLL16(Ctx + t1, ldsA + 4096);
        GLL16(WoH + bOff0 + k0, ldsB);
        GLL16(WoH + bOff1 + k0, ldsB + 4096);
        GLL16(WoL + bOff0 + k0, ldsB + 8192);
        GLL16(WoL + bOff1 + k0, ldsB + 12288);
        __syncthreads();

        short8 ah[4], bh[4], bl[4];
        #pragma unroll
        for (int t = 0; t < 4; ++t) {
            const int mr = wr * 64 + t * 16 + l15;
            const int pa = (q ^ ((mr >> 1) & 3)) * 8;
            ah[t] = *(const short8*)&As[mr * 32 + pa];
            const int nr = wc * 64 + t * 16 + l15;
            const int pb = (q ^ ((nr >> 1) & 3)) * 8;
            bh[t] = *(const short8*)&Bs[0][nr * 32 + pb];
            bl[t] = *(const short8*)&Bs[1][nr * 32 + pb];
        }
        #pragma unroll
        for (int mt = 0; mt < 4; ++mt)
            #pragma unroll
            for (int nt = 0; nt < 4; ++nt) {
                acc[mt][nt] = __builtin_amdgcn_mfma_f32_16x16x32_bf16(ah[mt], bh[nt], acc[mt][nt], 0, 0, 0);
                acc[mt][nt] = __builtin_amdgcn_mfma_f32_16x16x32_bf16(ah[mt], bl[nt], acc[mt][nt], 0, 0, 0);
            }
        __syncthreads();
    }

    #pragma unroll
    for (int nt = 0; nt < 4; ++nt) {
        const int col = n0 + wc * 64 + nt * 16 + l15;
        const float bcol = bo[col];
        #pragma unroll
        for (int mt = 0; mt < 4; ++mt) {
            const int rowB = m0 + wr * 64 + mt * 16 + q * 4;
            #pragma unroll
            for (int r = 0; r < 4; ++r)
                out[(long)(rowB + r) * H_DIM + col] = acc[mt][nt][r] + bcol;
        }
    }
}

extern "C" void kernel_launch(void* const* d_in, const int* in_sizes, int n_in,
                              void* d_out, int out_size, void* d_ws, size_t ws_size,
                              hipStream_t stream) {
    const float* X  = (const float*)d_in[0];
    const float* Wq = (const float*)d_in[1]; const float* bq = (const float*)d_in[2];
    const float* Wk = (const float*)d_in[3]; const float* bk = (const float*)d_in[4];
    const float* Wv = (const float*)d_in[5]; const float* bv = (const float*)d_in[6];
    const float* Wo = (const float*)d_in[7]; const float* bo = (const float*)d_in[8];

    unsigned short* wsu = (unsigned short*)d_ws;
    unsigned short* Qt  = wsu;                    // 25,165,824 shorts (Q hi/lo tiles; ctx in place)
    unsigned short* Kp  = wsu + 25165824L;        // 12,582,912 (bf16 [bmh][p][d])
    unsigned short* Vp  = Kp + 12582912L;         // 12,582,912 (bf16 [bmh][d][p])
    unsigned short* Wt  = Vp + 12582912L;         // 8 planes x 589,824
    const long WP = (long)H_DIM * H_DIM;
    unsigned short* WqH = Wt;          unsigned short* WqL = Wt + WP;
    unsigned short* WkH = Wt + 2 * WP; unsigned short* WkL = Wt + 3 * WP;
    unsigned short* WvH = Wt + 4 * WP; unsigned short* WvL = Wt + 5 * WP;
    unsigned short* WoH = Wt + 6 * WP; unsigned short* WoL = Wt + 7 * WP;

    // X~ lives in d_out (dead until oproj overwrites it)
    unsigned short* Xb = (unsigned short*)d_out;

    prep_x<<<(int)(SZT / 2048), 256, 0, stream>>>(X, Xb);
    dim3 wgrid(12, 12);
    prep_w<<<wgrid, 256, 0, stream>>>(Wq, WqH, WqL);
    prep_w<<<wgrid, 256, 0, stream>>>(Wk, WkH, WkL);
    prep_w<<<wgrid, 256, 0, stream>>>(Wv, WvH, WvL);
    prep_w<<<wgrid, 256, 0, stream>>>(Wo, WoH, WoL);

    const float qscale = 0.125f * 1.4426950408889634f;   // softmax in base-2 domain
    qkv_gemm<<<dim3(18, 128), 256, 0, stream>>>(Xb, WqH, WqL, WkH, WkL, WvH, WvL,
                                                bq, bk, bv, qscale, Qt, Kp, Vp);

    attn2<<<dim3(4, 384), 256, 0, stream>>>(Qt, Kp, Vp, Qt);

    oproj<<<dim3(6, 128), 256, 0, stream>>>(Qt, WoH, WoL, bo, (float*)d_out);
}

// Round 6
// 328.495 us; speedup vs baseline: 4.5926x; 1.2194x over previous
//
#include <hip/hip_runtime.h>
#include <cstdint>
#include <cstddef>

#define H_DIM 768
#define NHEADS 12
#define HSZ 64
#define PATCH 512
#define MTOT 16384                 // 8*4*512 tokens
#define SZT ((long)MTOT * H_DIM)   // elements per [16384,768] matrix

using short8 = __attribute__((ext_vector_type(8))) short;   // 8 bf16 (4 VGPRs)
using f32x4  = __attribute__((ext_vector_type(4))) float;   // MFMA accumulator
using us4    = __attribute__((ext_vector_type(4))) unsigned short;

// async global->LDS, 16B per lane; LDS dest = wave-uniform base + lane*16
#define GLL16(gp, lp) __builtin_amdgcn_global_load_lds( \
    (const __attribute__((address_space(1))) void*)(gp), \
    (__attribute__((address_space(3))) void*)(lp), 16, 0, 0)

// fp32 -> bf16 hi (truncate) + bf16 lo (RNE of remainder); hi+lo ~ 2^-17 rel err
__device__ __forceinline__ void split_f32(float x, unsigned short& h, unsigned short& l) {
    unsigned u = __float_as_uint(x);
    h = (unsigned short)(u >> 16);
    float rem = __uint_as_float(u & 0xffff0000u);
    float r = x - rem;                       // exact
    unsigned v = __float_as_uint(r);
    v += 0x7fff + ((v >> 16) & 1);           // RNE to bf16
    l = (unsigned short)(v >> 16);
}

__device__ __forceinline__ unsigned short bf16rne(float x) {
    unsigned v = __float_as_uint(x);
    v += 0x7fff + ((v >> 16) & 1);
    return (unsigned short)(v >> 16);
}

// ------------------------------------------------------------------
// prep_x: X fp32 [16384][768] -> X~ bf16 RNE row-major (stored in d_out)
// ------------------------------------------------------------------
__global__ __launch_bounds__(256) void prep_x(const float* __restrict__ X,
                                              unsigned short* __restrict__ Xb)
{
    const long i = ((long)blockIdx.x * 256 + threadIdx.x) * 8;
    float4 a = *(const float4*)&X[i];
    float4 b = *(const float4*)&X[i + 4];
    float xs[8] = {a.x, a.y, a.z, a.w, b.x, b.y, b.z, b.w};
    us4 h0, h1;
    #pragma unroll
    for (int j = 0; j < 4; ++j) { h0[j] = bf16rne(xs[j]); h1[j] = bf16rne(xs[j + 4]); }
    *(us4*)&Xb[i] = h0; *(us4*)&Xb[i + 4] = h1;
}

// ------------------------------------------------------------------
// prep_w: W fp32 [k][n] -> transposed bf16 [n][k]. LO=1 also writes the
// lo-residual plane (for Wo); LO=0 writes hi (RNE) only.
// ------------------------------------------------------------------
template<int LO>
__global__ __launch_bounds__(256) void prep_w(const float* __restrict__ W,
                                              unsigned short* __restrict__ Whi,
                                              unsigned short* __restrict__ Wlo)
{
    __shared__ float T[64][65];
    const int kt = blockIdx.x * 64, nt = blockIdx.y * 64;
    const int tid = threadIdx.x;
    const int r = tid >> 2, c16 = (tid & 3) * 16;
    #pragma unroll
    for (int j = 0; j < 4; ++j) {
        float4 v = *(const float4*)&W[(long)(kt + r) * H_DIM + nt + c16 + j * 4];
        T[r][c16 + j*4 + 0] = v.x; T[r][c16 + j*4 + 1] = v.y;
        T[r][c16 + j*4 + 2] = v.z; T[r][c16 + j*4 + 3] = v.w;
    }
    __syncthreads();
    unsigned short* ph = &Whi[(long)(nt + r) * H_DIM + kt + c16];
    #pragma unroll
    for (int j = 0; j < 16; ++j) {
        if (LO) {
            unsigned short hh, ll;
            split_f32(T[c16 + j][r], hh, ll);
            ph[j] = hh;
            Wlo[(long)(nt + r) * H_DIM + kt + c16 + j] = ll;
        } else {
            ph[j] = bf16rne(T[c16 + j][r]);
        }
    }
}

// ------------------------------------------------------------------
// qkv_gemm: fused Q/K/V projection, 1-pass bf16 MFMA (X~ x W~).
// grid (18, 128): mat = bx/6; 128x128 tile, BK=64, 4 waves, 32 KB LDS.
// XOR chunk swizzle: logical chunk c of row r at phys c^(r&7) -> 2-way banks.
// Epilogues: mat0 Q tiles bf16 (pre-scaled by 0.125*log2e), mat1 K [p][d],
//            mat2 V [d][p].
// ------------------------------------------------------------------
__global__ __launch_bounds__(256, 4) void qkv_gemm(
    const unsigned short* __restrict__ Xb,
    const unsigned short* __restrict__ WqH, const unsigned short* __restrict__ WkH,
    const unsigned short* __restrict__ WvH,
    const float* __restrict__ bq, const float* __restrict__ bk, const float* __restrict__ bv,
    float qscale,
    unsigned short* __restrict__ Qt, unsigned short* __restrict__ Kp,
    unsigned short* __restrict__ Vp)
{
    __shared__ unsigned short As[8192];      // 128 rows x 64 k (swizzled chunks)
    __shared__ unsigned short Bs[8192];

    const int mat = blockIdx.x / 6;
    const int n0  = (blockIdx.x % 6) * 128;
    const int m0  = blockIdx.y * 128;
    const unsigned short* Bh = (mat == 0) ? WqH : (mat == 1) ? WkH : WvH;
    const float* bias        = (mat == 0) ? bq  : (mat == 1) ? bk  : bv;
    const float scale        = (mat == 0) ? qscale : 1.0f;

    const int tid  = threadIdx.x;
    const int lane = tid & 63;
    const int wv   = tid >> 6;
    const int wr   = wv >> 1, wc = wv & 1;
    const int q    = lane >> 4, l15 = lane & 15;

    const int srow   = tid >> 3;                        // 0..31
    const int schunk = (tid & 7) ^ (srow & 7);          // swizzled global chunk

    char* ldsA = (char*)(&As[0]) + (wv << 10);
    char* ldsB = (char*)(&Bs[0]) + (wv << 10);

    f32x4 acc[4][4];
    #pragma unroll
    for (int i = 0; i < 4; ++i)
        #pragma unroll
        for (int j = 0; j < 4; ++j) acc[i][j] = 0;

    const int swz = (l15 & 7);   // row-dependent chunk swizzle for fragment reads

    for (int k0 = 0; k0 < H_DIM; k0 += 64) {
        #pragma unroll
        for (int i = 0; i < 4; ++i) {
            GLL16(Xb + (long)(m0 + i * 32 + srow) * H_DIM + k0 + schunk * 8,
                  ldsA + i * 4096);
            GLL16(Bh + (long)(n0 + i * 32 + srow) * H_DIM + k0 + schunk * 8,
                  ldsB + i * 4096);
        }
        __syncthreads();

        #pragma unroll
        for (int ks = 0; ks < 2; ++ks) {
            const int pc = ((ks * 4 + q) ^ swz) * 8;
            short8 ah[4], bh[4];
            #pragma unroll
            for (int t = 0; t < 4; ++t) {
                const int mr = wr * 64 + t * 16 + l15;
                ah[t] = *(const short8*)&As[mr * 64 + pc];
                const int nr = wc * 64 + t * 16 + l15;
                bh[t] = *(const short8*)&Bs[nr * 64 + pc];
            }
            #pragma unroll
            for (int mt = 0; mt < 4; ++mt)
                #pragma unroll
                for (int nt = 0; nt < 4; ++nt)
                    acc[mt][nt] = __builtin_amdgcn_mfma_f32_16x16x32_bf16(ah[mt], bh[nt], acc[mt][nt], 0, 0, 0);
        }
        __syncthreads();
    }

    // epilogue: C/D layout col = lane&15, row = quad*4 + reg
    #pragma unroll
    for (int nt = 0; nt < 4; ++nt) {
        const int col = n0 + wc * 64 + nt * 16 + l15;
        const float bcol = bias[col];
        const int h = col >> 6, d = col & 63;
        #pragma unroll
        for (int mt = 0; mt < 4; ++mt) {
            const int rowB = m0 + wr * 64 + mt * 16 + q * 4;
            #pragma unroll
            for (int r = 0; r < 4; ++r) {
                const int row = rowB + r;
                const float val = (acc[mt][nt][r] + bcol) * scale;
                const int bm = row >> 9, p = row & 511;
                const int bmh = bm * NHEADS + h;
                if (mat == 0) {
                    const long idx = ((long)bmh * 8 + (p >> 6)) * 4096 + (long)(p & 63) * 64 + d;
                    Qt[idx] = bf16rne(val);
                } else if (mat == 1) {
                    Kp[(long)bmh * 32768 + (long)p * 64 + d] = bf16rne(val);
                } else {
                    Vp[(long)bmh * 32768 + (long)d * 512 + p] = bf16rne(val);
                }
            }
        }
    }
}

// ------------------------------------------------------------------
// attn2: flash attention, no max-tracking (scores bounded; base-2 softmax,
// Q pre-scaled by 0.125*log2e). QK 1-pass, PV 1-pass, all bf16.
// 128 q-rows/block, 64-key tiles, 8 iters. ctx bf16 in place over Q tiles.
// ------------------------------------------------------------------
__global__ __launch_bounds__(256, 4) void attn2(
    const unsigned short* __restrict__ Qt,
    const unsigned short* __restrict__ Kp, const unsigned short* __restrict__ Vp,
    unsigned short* __restrict__ Ctx)
{
    __shared__ unsigned short Ks[4096];      // [key][swz-chunk*8] bf16
    __shared__ unsigned short Vs[4096];      // [d][swz-chunk*8] bf16
    __shared__ unsigned short Ps[128 * 72];  // P bf16, padded stride 72
    __shared__ float red[128][2];            // cross-wave row sum (finalize)

    const int tid  = threadIdx.x;
    const int lane = tid & 63;
    const int wv   = tid >> 6;
    const int wr   = wv >> 1, wc = wv & 1;
    const int q    = lane >> 4, l15 = lane & 15;
    const int qt2  = blockIdx.x;     // 0..3
    const int bmh  = blockIdx.y;     // 0..383

    // ---- Q fragments (loop-invariant) ----
    short8 qh[4][2];
    const long qtile = ((long)bmh * 8 + qt2 * 2 + wr) * 4096;
    #pragma unroll
    for (int mt = 0; mt < 4; ++mt)
        #pragma unroll
        for (int ks = 0; ks < 2; ++ks)
            qh[mt][ks] = *(const short8*)&Qt[qtile + (mt * 16 + l15) * 64 + ks * 32 + q * 8];

    f32x4 ctx[4][2];
    float l_cur[4][4];
    #pragma unroll
    for (int mt = 0; mt < 4; ++mt) {
        ctx[mt][0] = 0; ctx[mt][1] = 0;
        #pragma unroll
        for (int r = 0; r < 4; ++r) l_cur[mt][r] = 0.0f;
    }

    const long khead = (long)bmh * 32768;
    const int srow   = tid >> 3;                               // 0..31
    const int gchunk = ((tid & 7) ^ (srow & 7)) * 8;           // swizzled source chunk
    char* dK = (char*)&Ks[0] + (wv << 10);
    char* dV = (char*)&Vs[0] + (wv << 10);

    for (int kt = 0; kt < 8; ++kt) {
        __syncthreads();   // prev iter's QK/PV reads of Ks/Vs/Ps complete
        {
            const long kb = khead + (long)kt * 64 * 64;
            GLL16(Kp + kb + (long)srow * 64 + gchunk,        dK);
            GLL16(Kp + kb + (long)(srow + 32) * 64 + gchunk, dK + 4096);
            const long vb = khead + (long)kt * 64;
            GLL16(Vp + vb + (long)srow * 512 + gchunk,        dV);
            GLL16(Vp + vb + (long)(srow + 32) * 512 + gchunk, dV + 4096);
        }
        __syncthreads();   // staging landed (barrier drains vmcnt)

        // ---- S = Q K^T (1-pass) : rows wr*64+, keys wc*32+ ----
        f32x4 s[4][2];
        #pragma unroll
        for (int mt = 0; mt < 4; ++mt) { s[mt][0] = 0; s[mt][1] = 0; }
        short8 kf[2][2];
        #pragma unroll
        for (int nt = 0; nt < 2; ++nt)
            #pragma unroll
            for (int ks = 0; ks < 2; ++ks) {
                const int key = wc * 32 + nt * 16 + l15;
                const int phys = (q + ks * 4) ^ (key & 7);
                kf[nt][ks] = *(const short8*)&Ks[key * 64 + phys * 8];
            }
        #pragma unroll
        for (int mt = 0; mt < 4; ++mt)
            #pragma unroll
            for (int nt = 0; nt < 2; ++nt)
                #pragma unroll
                for (int ks = 0; ks < 2; ++ks)
                    s[mt][nt] = __builtin_amdgcn_mfma_f32_16x16x32_bf16(qh[mt][ks], kf[nt][ks], s[mt][nt], 0, 0, 0);

        // ---- p = exp2(s); accumulate l; write P bf16 ----
        #pragma unroll
        for (int mt = 0; mt < 4; ++mt)
            #pragma unroll
            for (int r = 0; r < 4; ++r) {
                const int row = wr * 64 + mt * 16 + q * 4 + r;
                const float p0 = __builtin_amdgcn_exp2f(s[mt][0][r]);
                const float p1 = __builtin_amdgcn_exp2f(s[mt][1][r]);
                l_cur[mt][r] += p0 + p1;
                Ps[row * 72 + wc * 32 + l15]      = bf16rne(p0);
                Ps[row * 72 + wc * 32 + 16 + l15] = bf16rne(p1);
            }
        __syncthreads();

        // ---- ctx += P V (1-pass) : rows wr*64+, d-cols wc*32+ ----
        short8 pf[4][2], vf[2][2];
        #pragma unroll
        for (int mt = 0; mt < 4; ++mt)
            #pragma unroll
            for (int ks = 0; ks < 2; ++ks)
                pf[mt][ks] = *(const short8*)&Ps[(wr * 64 + mt * 16 + l15) * 72 + ks * 32 + q * 8];
        #pragma unroll
        for (int nt = 0; nt < 2; ++nt)
            #pragma unroll
            for (int ks = 0; ks < 2; ++ks) {
                const int d = wc * 32 + nt * 16 + l15;
                const int phys = (q + ks * 4) ^ (d & 7);
                vf[nt][ks] = *(const short8*)&Vs[d * 64 + phys * 8];
            }
        #pragma unroll
        for (int mt = 0; mt < 4; ++mt)
            #pragma unroll
            for (int nt = 0; nt < 2; ++nt)
                #pragma unroll
                for (int ks = 0; ks < 2; ++ks)
                    ctx[mt][nt] = __builtin_amdgcn_mfma_f32_16x16x32_bf16(pf[mt][ks], vf[nt][ks], ctx[mt][nt], 0, 0, 0);
    }

    // ---- finalize l (in-quad + cross-wave sum), normalize, store ctx bf16 ----
    #pragma unroll
    for (int mt = 0; mt < 4; ++mt)
        #pragma unroll
        for (int r = 0; r < 4; ++r) {
            float v = l_cur[mt][r];
            v += __shfl_xor(v, 1);
            v += __shfl_xor(v, 2);
            v += __shfl_xor(v, 4);
            v += __shfl_xor(v, 8);
            if (l15 == 0) red[wr * 64 + mt * 16 + q * 4 + r][wc] = v;
        }
    __syncthreads();
    #pragma unroll
    for (int mt = 0; mt < 4; ++mt)
        #pragma unroll
        for (int r = 0; r < 4; ++r) {
            const int row = wr * 64 + mt * 16 + q * 4 + r;
            const float2 rd = *(const float2*)&red[row][0];
            const float inv = 1.0f / (rd.x + rd.y);
            const int trow = mt * 16 + q * 4 + r;
            #pragma unroll
            for (int nt = 0; nt < 2; ++nt) {
                const int col = wc * 32 + nt * 16 + l15;
                Ctx[qtile + trow * 64 + col] = bf16rne(ctx[mt][nt][r] * inv);
            }
        }
}

// ------------------------------------------------------------------
// oproj: Out = ctx @ Wo + bo, 2-pass MFMA (ctx bf16 x Wo hi/lo), BK=64.
// A from ctx tiles (stride 4096). Out fp32 row-major. 48 KB LDS.
// ------------------------------------------------------------------
__global__ __launch_bounds__(256, 3) void oproj(
    const unsigned short* __restrict__ Ctx,
    const unsigned short* __restrict__ WoH, const unsigned short* __restrict__ WoL,
    const float* __restrict__ bo, float* __restrict__ out)
{
    __shared__ unsigned short As[8192];
    __shared__ unsigned short Bs[2][8192];

    const int tid  = threadIdx.x;
    const int lane = tid & 63;
    const int wv   = tid >> 6;
    const int wr   = wv >> 1, wc = wv & 1;
    const int q    = lane >> 4, l15 = lane & 15;
    const int m0   = blockIdx.y * 128;
    const int n0   = blockIdx.x * 128;

    const int srow   = tid >> 3;
    const int schunk = (tid & 7) ^ (srow & 7);

    char* ldsA = (char*)(&As[0]) + (wv << 10);
    char* ldsB = (char*)(&Bs[0][0]) + (wv << 10);

    f32x4 acc[4][4];
    #pragma unroll
    for (int i = 0; i < 4; ++i)
        #pragma unroll
        for (int j = 0; j < 4; ++j) acc[i][j] = 0;

    const int swz = (l15 & 7);

    for (int k0 = 0; k0 < H_DIM; k0 += 64) {
        const int h = k0 >> 6;   // BK=64 == head size: one head per k-iter
        #pragma unroll
        for (int i = 0; i < 4; ++i) {
            const int tok = m0 + i * 32 + srow;
            const long tile = ((long)(tok >> 9) * NHEADS + h) * 8 + ((tok >> 6) & 7);
            GLL16(Ctx + tile * 4096 + (long)(tok & 63) * 64 + schunk * 8, ldsA + i * 4096);
            GLL16(WoH + (long)(n0 + i * 32 + srow) * H_DIM + k0 + schunk * 8, ldsB + i * 4096);
            GLL16(WoL + (long)(n0 + i * 32 + srow) * H_DIM + k0 + schunk * 8, ldsB + 16384 + i * 4096);
        }
        __syncthreads();

        #pragma unroll
        for (int ks = 0; ks < 2; ++ks) {
            const int pc = ((ks * 4 + q) ^ swz) * 8;
            short8 ah[4], bh[4], bl[4];
            #pragma unroll
            for (int t = 0; t < 4; ++t) {
                const int mr = wr * 64 + t * 16 + l15;
                ah[t] = *(const short8*)&As[mr * 64 + pc];
                const int nr = wc * 64 + t * 16 + l15;
                bh[t] = *(const short8*)&Bs[0][nr * 64 + pc];
                bl[t] = *(const short8*)&Bs[1][nr * 64 + pc];
            }
            #pragma unroll
            for (int mt = 0; mt < 4; ++mt)
                #pragma unroll
                for (int nt = 0; nt < 4; ++nt) {
                    acc[mt][nt] = __builtin_amdgcn_mfma_f32_16x16x32_bf16(ah[mt], bh[nt], acc[mt][nt], 0, 0, 0);
                    acc[mt][nt] = __builtin_amdgcn_mfma_f32_16x16x32_bf16(ah[mt], bl[nt], acc[mt][nt], 0, 0, 0);
                }
        }
        __syncthreads();
    }

    #pragma unroll
    for (int nt = 0; nt < 4; ++nt) {
        const int col = n0 + wc * 64 + nt * 16 + l15;
        const float bcol = bo[col];
        #pragma unroll
        for (int mt = 0; mt < 4; ++mt) {
            const int rowB = m0 + wr * 64 + mt * 16 + q * 4;
            #pragma unroll
            for (int r = 0; r < 4; ++r)
                out[(long)(rowB + r) * H_DIM + col] = acc[mt][nt][r] + bcol;
        }
    }
}

extern "C" void kernel_launch(void* const* d_in, const int* in_sizes, int n_in,
                              void* d_out, int out_size, void* d_ws, size_t ws_size,
                              hipStream_t stream) {
    const float* X  = (const float*)d_in[0];
    const float* Wq = (const float*)d_in[1]; const float* bq = (const float*)d_in[2];
    const float* Wk = (const float*)d_in[3]; const float* bk = (const float*)d_in[4];
    const float* Wv = (const float*)d_in[5]; const float* bv = (const float*)d_in[6];
    const float* Wo = (const float*)d_in[7]; const float* bo = (const float*)d_in[8];

    unsigned short* wsu = (unsigned short*)d_ws;
    unsigned short* Qt  = wsu;                    // 12,582,912 (Q tiles bf16; ctx in place)
    unsigned short* Kp  = Qt + 12582912L;         // 12,582,912 (bf16 [bmh][p][d])
    unsigned short* Vp  = Kp + 12582912L;         // 12,582,912 (bf16 [bmh][d][p])
    unsigned short* Wt  = Vp + 12582912L;         // 5 planes x 589,824
    const long WP = (long)H_DIM * H_DIM;
    unsigned short* WqH = Wt;
    unsigned short* WkH = Wt + WP;
    unsigned short* WvH = Wt + 2 * WP;
    unsigned short* WoH = Wt + 3 * WP;
    unsigned short* WoL = Wt + 4 * WP;

    // X~ lives in d_out (dead until oproj overwrites it)
    unsigned short* Xb = (unsigned short*)d_out;

    prep_x<<<(int)(SZT / 2048), 256, 0, stream>>>(X, Xb);
    dim3 wgrid(12, 12);
    prep_w<0><<<wgrid, 256, 0, stream>>>(Wq, WqH, nullptr);
    prep_w<0><<<wgrid, 256, 0, stream>>>(Wk, WkH, nullptr);
    prep_w<0><<<wgrid, 256, 0, stream>>>(Wv, WvH, nullptr);
    prep_w<1><<<wgrid, 256, 0, stream>>>(Wo, WoH, WoL);

    const float qscale = 0.125f * 1.4426950408889634f;   // softmax in base-2 domain
    qkv_gemm<<<dim3(18, 128), 256, 0, stream>>>(Xb, WqH, WkH, WvH,
                                                bq, bk, bv, qscale, Qt, Kp, Vp);

    attn2<<<dim3(4, 384), 256, 0, stream>>>(Qt, Kp, Vp, Qt);

    oproj<<<dim3(6, 128), 256, 0, stream>>>(Qt, WoH, WoL, bo, (float*)d_out);
}